// Round 6
// baseline (919.462 us; speedup 1.0000x reference)
//
#include <hip/hip_runtime.h>
#include <hip/hip_fp16.h>
#include <hip/hip_bf16.h>
#include <math.h>

#define N_NODES 51200
#define N_EDGES 819200
#define NB 64
#define CAP 64  // max in-degree; Binomial(E,1/N) mean 16, P(>=64) ~ 1e-19

typedef __attribute__((ext_vector_type(8))) short short8;
typedef __attribute__((ext_vector_type(4))) float float4v;

__device__ __forceinline__ float eluf(float x) {
  return x > 0.f ? x : expm1f(x);
}

__device__ __forceinline__ unsigned short f2bf(float v) {
  union { __hip_bfloat16 h; unsigned short u; } cv;
  cv.h = __float2bfloat16(v);
  return cv.u;
}
__device__ __forceinline__ unsigned pack2(float a, float b) {
  return (unsigned)f2bf(a) | ((unsigned)f2bf(b) << 16);
}

// Build dst-CSR with fixed-capacity buckets; pack {src|K<<16, half2(f0,f1)}.
// cnt doubles as degree. (src < 65536 fits 16 bits.)
__global__ __launch_bounds__(256) void scatter_eid(const int* __restrict__ ei,
                                                   const float* __restrict__ pseudo,
                                                   int* __restrict__ cnt,
                                                   int2* __restrict__ bucket) {
  int e = blockIdx.x * 256 + threadIdx.x;
  int src = ei[e], dst = ei[N_EDGES + e];
  float v0 = pseudo[2 * e] * 4.f;
  float v1 = pseudo[2 * e + 1] * 4.f;
  int lo0 = min(max((int)floorf(v0), 0), 3);
  int lo1 = min(max((int)floorf(v1), 0), 3);
  float f0 = v0 - (float)lo0, f1 = v1 - (float)lo1;
  int K = lo0 * 5 + lo1;  // corners at K, K+1, K+5, K+6
  unsigned short u0 = __half_as_ushort(__float2half(f0));
  unsigned short u1 = __half_as_ushort(__float2half(f1));
  int w0 = src | (K << 16);
  int w1 = (int)((unsigned)u0 | ((unsigned)u1 << 16));
  int slot = atomicAdd(&cnt[dst], 1);
  if (slot < CAP) bucket[(size_t)dst * CAP + slot] = make_int2(w0, w1);
}

// W2T[n][k] (bf16, n in [0,64), k in [0,832)): k<800 -> W2[k][n], else root2[k-800][n].
// 26624 uint pairs, grid 104 x 256.
__global__ __launch_bounds__(256) void build_w2t(const float* __restrict__ W2,
                                                 const float* __restrict__ root2,
                                                 unsigned short* __restrict__ W2T) {
  int p = blockIdx.x * 256 + threadIdx.x;
  int n = p / 416, kp = p - n * 416, k = kp * 2;
  float v0 = (k < 800) ? W2[k * 64 + n] : root2[(k - 800) * 64 + n];
  float v1 = (k + 1 < 800) ? W2[(k + 1) * 64 + n] : root2[(k + 1 - 800) * 64 + n];
  ((unsigned*)W2T)[n * 416 + kp] = pack2(v0, v1);
}

// Layer 1 fused: per block, T[32 nodes][175] in LDS via ds_add (4 edges/wave-iter),
// then h1 = elu( (T @ W1)/deg + x @ root1 + b1 ).
#define L1_NODES 32
__global__ __launch_bounds__(256) void fused_l1(const int2* __restrict__ bucket,
                                                const int* __restrict__ cnt,
                                                const float* __restrict__ x,
                                                const float* __restrict__ W1,
                                                const float* __restrict__ root1,
                                                const float* __restrict__ b1,
                                                float* __restrict__ h1) {
  __shared__ float T[L1_NODES * 175];  // 22.4 KB
  int tid = threadIdx.x;
  int n0 = blockIdx.x * L1_NODES;
  for (int idx = tid; idx < L1_NODES * 175; idx += 256) T[idx] = 0.f;
  __syncthreads();
  // Phase A: wave wv -> nodes wv, wv+4, ...; 4 edges per iteration:
  // lane = e2*16 + s2*8 + i  (i<7 active). LDS atomics make collisions safe.
  int wv = tid >> 6, l = tid & 63;
  int e2 = l >> 4, i = l & 7, s2 = (l >> 3) & 1;
  bool act = i < 7;
  for (int nn = wv; nn < L1_NODES; nn += 4) {
    int n = n0 + nn;
    int dg = min(cnt[n], CAP);
    float* Tn = &T[nn * 175];
    const int2* bk = bucket + (size_t)n * CAP;
    for (int j = 0; j < dg; j += 4) {
      int jj = j + e2;
      if (jj < dg && act) {
        int2 rec = bk[jj];
        int src = rec.x & 0xFFFF, K = rec.x >> 16;
        unsigned pv = (unsigned)rec.y;
        float f0 = __half2float(__ushort_as_half((unsigned short)(pv & 0xFFFF)));
        float f1 = __half2float(__ushort_as_half((unsigned short)(pv >> 16)));
        float xv = x[src * 7 + i];
        float bc = s2 ? f1 : 1.f - f1;
        atomicAdd(&Tn[(K + s2) * 7 + i], (1.f - f0) * bc * xv);
        atomicAdd(&Tn[(K + 5 + s2) * 7 + i], f0 * bc * xv);
      }
    }
  }
  __syncthreads();
  // Phase B: thread (o, g): 4 nodes g, g+8, g+16, g+24; W1 via L1 cache.
  int o = tid & 31, g = tid >> 5;
  float acc[4] = {0.f, 0.f, 0.f, 0.f};
  for (int kk = 0; kk < 175; kk++) {
    float w = W1[kk * 32 + o];
#pragma unroll
    for (int q = 0; q < 4; q++) acc[q] += T[(g + q * 8) * 175 + kk] * w;
  }
#pragma unroll
  for (int q = 0; q < 4; q++) {
    int n = n0 + g + q * 8;
    float dv = fmaxf((float)cnt[n], 1.f);
    float v = acc[q] / dv + b1[o];
    const float* xr = x + (size_t)n * 7;
#pragma unroll
    for (int jj = 0; jj < 7; jj++) v += xr[jj] * root1[jj * 32 + o];
    h1[(size_t)n * 32 + o] = eluf(v);
  }
}

// Layer 2 fused: per block, T[16 nodes][800] fp32 in LDS via ds_add; then
// scale by 1/deg, cast bf16 in place, append h1 (32 cols), and
// MFMA: [T/deg | h1](16x832) @ [W2;root2]T -> h2 = elu(. + b2).
// Tb rows padded to 840 bf16 (1680 B) to break LDS bank alignment.
#define L2N 16
__global__ __launch_bounds__(256) void fused_l2(const int2* __restrict__ bucket,
                                                const int* __restrict__ cnt,
                                                const float* __restrict__ h1,
                                                const unsigned short* __restrict__ W2T,
                                                const float* __restrict__ b2,
                                                float* __restrict__ h2) {
  __shared__ float T[L2N * 800];  // 51.2 KB; reused as bf16 Tb[16][840]
  __shared__ float invdeg_s[L2N];
  int tid = threadIdx.x;
  int n0 = blockIdx.x * L2N;
  {
    float2* t2 = (float2*)T;
    for (int idx = tid; idx < L2N * 400; idx += 256) t2[idx] = make_float2(0.f, 0.f);
  }
  if (tid < L2N) invdeg_s[tid] = 1.f / fmaxf((float)cnt[n0 + tid], 1.f);
  __syncthreads();
  // Phase A: wave wv -> nodes wv, wv+4, ...; lane: i=l&31 (feature), s2=l>>5.
  int wv = tid >> 6, l = tid & 63;
  {
    int i = l & 31, s2 = l >> 5;
    for (int nn = wv; nn < L2N; nn += 4) {
      int n = n0 + nn;
      int dg = min(cnt[n], CAP);
      float* Tn = &T[nn * 800];
      const int2* bk = bucket + (size_t)n * CAP;
#pragma unroll 2
      for (int j = 0; j < dg; j++) {
        int2 rec = bk[j];
        int src = rec.x & 0xFFFF, K = rec.x >> 16;
        unsigned pv = (unsigned)rec.y;
        float f0 = __half2float(__ushort_as_half((unsigned short)(pv & 0xFFFF)));
        float f1 = __half2float(__ushort_as_half((unsigned short)(pv >> 16)));
        float hv = h1[(size_t)src * 32 + i];
        float bc = s2 ? f1 : (1.f - f1);
        atomicAdd(&Tn[(K + s2) * 32 + i], (1.f - f0) * bc * hv);
        atomicAdd(&Tn[(K + 5 + s2) * 32 + i], f0 * bc * hv);
      }
    }
  }
  __syncthreads();
  // Convert: stage 25 float2/thread in regs, then rewrite as bf16 (row*420 uints).
  float2 st[25];
#pragma unroll
  for (int r = 0; r < 25; r++) {
    int p = tid + 256 * r;           // pair index over 16x800 fp32
    int row = p / 400, col2 = p - row * 400;
    float2 v = *(const float2*)&T[row * 800 + col2 * 2];
    float s = invdeg_s[row];
    st[r] = make_float2(v.x * s, v.y * s);
  }
  __syncthreads();
  unsigned* Tb = (unsigned*)T;
#pragma unroll
  for (int r = 0; r < 25; r++) {
    int p = tid + 256 * r;
    int row = p / 400, col2 = p - row * 400;
    Tb[row * 420 + col2] = pack2(st[r].x, st[r].y);
  }
  {  // append h1 (no deg scale) as K-cols 800..831
    int row = tid >> 4, c2 = tid & 15;
    float2 hv = *(const float2*)&h1[(size_t)(n0 + row) * 32 + c2 * 2];
    Tb[row * 420 + 400 + c2] = pack2(hv.x, hv.y);
  }
  __syncthreads();
  // MFMA phase: wave wv computes nodes 0..15 x feats [wv*16, wv*16+16).
  int m = l & 15, quad = l >> 4;
  const char* abase = (const char*)T + m * 1680 + quad * 16;
  const unsigned short* bbase = W2T + (size_t)(wv * 16 + m) * 832 + quad * 8;
  float4v acc = {0.f, 0.f, 0.f, 0.f};
  for (int it = 0; it < 26; it++) {
    short8 af = *(const short8*)(abase + it * 64);
    short8 bf = *(const short8*)(bbase + it * 32);
    acc = __builtin_amdgcn_mfma_f32_16x16x32_bf16(af, bf, acc, 0, 0, 0);
  }
  int feat = wv * 16 + m;
  float bb = b2[feat];
#pragma unroll
  for (int r = 0; r < 4; r++) {
    int node = n0 + quad * 4 + r;
    h2[(size_t)node * 64 + feat] = eluf(acc[r] + bb);
  }
}

// Mean-pool h2 over each slice range -> gbuf[g][64]
__global__ __launch_bounds__(256) void pool(const float* __restrict__ h2,
                                            const int* __restrict__ slices,
                                            float* __restrict__ gbuf) {
  int g = blockIdx.x;
  int tid = threadIdx.x;
  int o = tid & 63, q = tid >> 6;
  int s0 = slices[g], s1 = slices[g + 1];
  float p = 0.f;
  for (int n = s0 + q; n < s1; n += 4) p += h2[(size_t)n * 64 + o];
  __shared__ float red[4][64];
  red[q][o] = p;
  __syncthreads();
  if (q == 0) {
    float s = red[0][o] + red[1][o] + red[2][o] + red[3][o];
    float cnt2 = (float)(s1 - s0);
    gbuf[g * 64 + o] = s / fmaxf(cnt2, 1.f);
  }
}

// FC(64->30) + log_softmax. One block (64 thr) per group; lanes 0..29 active.
__global__ __launch_bounds__(64) void fc_ls(const float* __restrict__ gbuf,
                                            const float* __restrict__ fcw,
                                            const float* __restrict__ fcb,
                                            float* __restrict__ out) {
  int g = blockIdx.x;
  int l = threadIdx.x;
  float logit = -INFINITY;
  if (l < 30) {
    float acc = fcb[l];
    for (int i = 0; i < 64; i++) acc += gbuf[g * 64 + i] * fcw[i * 30 + l];
    logit = acc;
  }
  float m = logit;
  for (int off = 16; off; off >>= 1) m = fmaxf(m, __shfl_xor(m, off, 32));
  float e = (l < 30) ? expf(logit - m) : 0.f;
  for (int off = 16; off; off >>= 1) e += __shfl_xor(e, off, 32);
  if (l < 30) out[g * 30 + l] = logit - m - logf(e);
}

extern "C" void kernel_launch(void* const* d_in, const int* in_sizes, int n_in,
                              void* d_out, int out_size, void* d_ws, size_t ws_size,
                              hipStream_t stream) {
  const float* x      = (const float*)d_in[0];
  const int*   ei     = (const int*)d_in[1];
  const float* pseudo = (const float*)d_in[2];
  const int*   slices = (const int*)d_in[3];
  const float* W1     = (const float*)d_in[4];
  const float* root1  = (const float*)d_in[5];
  const float* b1     = (const float*)d_in[6];
  const float* W2     = (const float*)d_in[7];
  const float* root2  = (const float*)d_in[8];
  const float* b2     = (const float*)d_in[9];
  const float* fcw    = (const float*)d_in[10];
  const float* fcb    = (const float*)d_in[11];
  float* out = (float*)d_out;

  char* ws = (char*)d_ws;
  int*   cnt    = (int*)ws;                                    // N ints
  int2*  bucket = (int2*)(cnt + N_NODES);                      // N*CAP int2 (26.2 MB)
  float* h1     = (float*)(bucket + (size_t)N_NODES * CAP);    // N*32
  float* h2     = h1 + (size_t)N_NODES * 32;                   // N*64
  float* gbuf   = h2 + (size_t)N_NODES * 64;                   // 64*64
  unsigned short* W2T = (unsigned short*)(gbuf + 64 * 64);     // 64*832 bf16

  hipMemsetAsync(cnt, 0, N_NODES * sizeof(int), stream);

  build_w2t<<<104, 256, 0, stream>>>(W2, root2, W2T);
  scatter_eid<<<N_EDGES / 256, 256, 0, stream>>>(ei, pseudo, cnt, bucket);
  fused_l1<<<N_NODES / L1_NODES, 256, 0, stream>>>(bucket, cnt, x, W1, root1, b1, h1);
  fused_l2<<<N_NODES / L2N, 256, 0, stream>>>(bucket, cnt, h1, W2T, b2, h2);
  pool<<<NB, 256, 0, stream>>>(h2, slices, gbuf);
  fc_ls<<<NB, 64, 0, stream>>>(gbuf, fcw, fcb, out);
}

// Round 7
// 410.144 us; speedup vs baseline: 2.2418x; 2.2418x over previous
//
#include <hip/hip_runtime.h>
#include <hip/hip_fp16.h>
#include <hip/hip_bf16.h>
#include <math.h>

#define N_NODES 51200
#define N_EDGES 819200
#define NB 64
#define CAP 64  // max in-degree; Binomial(E,1/N) mean 16, P(>=64) ~ 1e-19

typedef __attribute__((ext_vector_type(8))) short short8;
typedef __attribute__((ext_vector_type(4))) float float4v;

__device__ __forceinline__ float eluf(float x) {
  return x > 0.f ? x : expm1f(x);
}

__device__ __forceinline__ unsigned short f2bf(float v) {
  union { __hip_bfloat16 h; unsigned short u; } cv;
  cv.h = __float2bfloat16(v);
  return cv.u;
}
__device__ __forceinline__ unsigned pack2(float a, float b) {
  return (unsigned)f2bf(a) | ((unsigned)f2bf(b) << 16);
}

// Build dst-CSR with fixed-capacity buckets; pack {src|K<<16, half2(f0,f1)}.
// cnt doubles as degree. (src < 65536 fits 16 bits.)
__global__ __launch_bounds__(256) void scatter_eid(const int* __restrict__ ei,
                                                   const float* __restrict__ pseudo,
                                                   int* __restrict__ cnt,
                                                   int2* __restrict__ bucket) {
  int e = blockIdx.x * 256 + threadIdx.x;
  int src = ei[e], dst = ei[N_EDGES + e];
  float v0 = pseudo[2 * e] * 4.f;
  float v1 = pseudo[2 * e + 1] * 4.f;
  int lo0 = min(max((int)floorf(v0), 0), 3);
  int lo1 = min(max((int)floorf(v1), 0), 3);
  float f0 = v0 - (float)lo0, f1 = v1 - (float)lo1;
  int K = lo0 * 5 + lo1;  // corners at K, K+1, K+5, K+6
  unsigned short u0 = __half_as_ushort(__float2half(f0));
  unsigned short u1 = __half_as_ushort(__float2half(f1));
  int w0 = src | (K << 16);
  int w1 = (int)((unsigned)u0 | ((unsigned)u1 << 16));
  int slot = atomicAdd(&cnt[dst], 1);
  if (slot < CAP) bucket[(size_t)dst * CAP + slot] = make_int2(w0, w1);
}

// W2T[n][k] (bf16, n in [0,64), k in [0,832)): k<800 -> W2[k][n], else root2[k-800][n].
__global__ __launch_bounds__(256) void build_w2t(const float* __restrict__ W2,
                                                 const float* __restrict__ root2,
                                                 unsigned short* __restrict__ W2T) {
  int p = blockIdx.x * 256 + threadIdx.x;
  int n = p / 416, kp = p - n * 416, k = kp * 2;
  float v0 = (k < 800) ? W2[k * 64 + n] : root2[(k - 800) * 64 + n];
  float v1 = (k + 1 < 800) ? W2[(k + 1) * 64 + n] : root2[(k + 1 - 800) * 64 + n];
  ((unsigned*)W2T)[n * 416 + kp] = pack2(v0, v1);
}

// Layer 1 fused: per block, T[32 nodes][175] in LDS (explicit race-free RMW),
// then h1 = elu( (T @ W1)/deg + x @ root1 + b1 ).
#define L1_NODES 32
__global__ __launch_bounds__(256) void fused_l1(const int2* __restrict__ bucket,
                                                const int* __restrict__ cnt,
                                                const float* __restrict__ x,
                                                const float* __restrict__ W1,
                                                const float* __restrict__ root1,
                                                const float* __restrict__ b1,
                                                float* __restrict__ h1) {
  __shared__ float T[L1_NODES * 175];  // 22.4 KB
  int tid = threadIdx.x;
  int n0 = blockIdx.x * L1_NODES;
  for (int idx = tid; idx < L1_NODES * 175; idx += 256) T[idx] = 0.f;
  __syncthreads();
  // Phase A: wave wv -> nodes wv, wv+4, ... Lane l<32: s=(l>>3)&3 (corner),
  // i=l&7 (feature, i<7 active). All 28 active addresses distinct -> race-free.
  int wv = tid >> 6, l = tid & 63;
  int s = (l >> 3) & 3, i = l & 7;
  bool act = (l < 32) && (i < 7);
  for (int nn = wv; nn < L1_NODES; nn += 4) {
    int n = n0 + nn;
    int dg = min(cnt[n], CAP);
    float* Tn = &T[nn * 175];
    const int2* bk = bucket + (size_t)n * CAP;
#pragma unroll 2
    for (int j = 0; j < dg; j++) {
      int2 rec = bk[j];
      int src = rec.x & 0xFFFF, K = rec.x >> 16;
      unsigned pv = (unsigned)rec.y;
      float f0 = __half2float(__ushort_as_half((unsigned short)(pv & 0xFFFF)));
      float f1 = __half2float(__ushort_as_half((unsigned short)(pv >> 16)));
      if (act) {
        float b0 = (s & 2) ? f0 : 1.f - f0;
        float bw = (s & 1) ? f1 : 1.f - f1;
        int ko = K + (s >> 1) * 5 + (s & 1);
        Tn[ko * 7 + i] += b0 * bw * x[src * 7 + i];
      }
    }
  }
  __syncthreads();
  // Phase B: thread (o, g): 4 nodes g, g+8, g+16, g+24; W1 via L1 cache.
  int o = tid & 31, g = tid >> 5;
  float acc[4] = {0.f, 0.f, 0.f, 0.f};
  for (int kk = 0; kk < 175; kk++) {
    float w = W1[kk * 32 + o];
#pragma unroll
    for (int q = 0; q < 4; q++) acc[q] += T[(g + q * 8) * 175 + kk] * w;
  }
#pragma unroll
  for (int q = 0; q < 4; q++) {
    int n = n0 + g + q * 8;
    float dv = fmaxf((float)cnt[n], 1.f);
    float v = acc[q] / dv + b1[o];
    const float* xr = x + (size_t)n * 7;
#pragma unroll
    for (int jj = 0; jj < 7; jj++) v += xr[jj] * root1[jj * 32 + o];
    h1[(size_t)n * 32 + o] = eluf(v);
  }
}

// Layer 2 fused: per block, T[16 nodes][800] fp32 in LDS via explicit race-free
// RMW (one edge per wave-iter; lane = corner-pair x 32 features); then scale by
// 1/deg, cast bf16 in place (rows padded to 840), append h1 (32 cols), and
// MFMA: [T/deg | h1](16x832) @ [W2;root2]T -> h2 = elu(. + b2).
#define L2N 16
__global__ __launch_bounds__(256) void fused_l2(const int2* __restrict__ bucket,
                                                const int* __restrict__ cnt,
                                                const float* __restrict__ h1,
                                                const unsigned short* __restrict__ W2T,
                                                const float* __restrict__ b2,
                                                float* __restrict__ h2) {
  __shared__ float T[L2N * 800];  // 51.2 KB; reused as bf16 Tb[16][840]
  __shared__ float invdeg_s[L2N];
  int tid = threadIdx.x;
  int n0 = blockIdx.x * L2N;
  {
    float2* t2 = (float2*)T;
    for (int idx = tid; idx < L2N * 400; idx += 256) t2[idx] = make_float2(0.f, 0.f);
  }
  if (tid < L2N) invdeg_s[tid] = 1.f / fmaxf((float)cnt[n0 + tid], 1.f);
  __syncthreads();
  // Phase A: wave wv -> nodes wv, wv+4, ...; lane: i=l&31 (feature), s2=l>>5
  // (corner pair). Corner planes {K,K+1} vs {K+5,K+6} disjoint; all 64 lane
  // addresses distinct -> race-free explicit RMW (no atomics!).
  int wv = tid >> 6, l = tid & 63;
  {
    int i = l & 31, s2 = l >> 5;
    for (int nn = wv; nn < L2N; nn += 4) {
      int n = n0 + nn;
      int dg = min(cnt[n], CAP);
      float* Tn = &T[nn * 800];
      const int2* bk = bucket + (size_t)n * CAP;
#pragma unroll 2
      for (int j = 0; j < dg; j++) {
        int2 rec = bk[j];
        int src = rec.x & 0xFFFF, K = rec.x >> 16;
        unsigned pv = (unsigned)rec.y;
        float f0 = __half2float(__ushort_as_half((unsigned short)(pv & 0xFFFF)));
        float f1 = __half2float(__ushort_as_half((unsigned short)(pv >> 16)));
        float hv = h1[(size_t)src * 32 + i];
        float bc = s2 ? f1 : (1.f - f1);
        float* ta = &Tn[(K + s2) * 32 + i];
        float* tb = &Tn[(K + 5 + s2) * 32 + i];
        float va = *ta + (1.f - f0) * bc * hv;
        float vb = *tb + f0 * bc * hv;
        *ta = va;
        *tb = vb;
      }
    }
  }
  __syncthreads();
  // Convert: stage 25 float2/thread in regs, then rewrite as bf16 (row*420 uints).
  float2 st[25];
#pragma unroll
  for (int r = 0; r < 25; r++) {
    int p = tid + 256 * r;           // pair index over 16x800 fp32
    int row = p / 400, col2 = p - row * 400;
    float2 v = *(const float2*)&T[row * 800 + col2 * 2];
    float s = invdeg_s[row];
    st[r] = make_float2(v.x * s, v.y * s);
  }
  __syncthreads();
  unsigned* Tb = (unsigned*)T;
#pragma unroll
  for (int r = 0; r < 25; r++) {
    int p = tid + 256 * r;
    int row = p / 400, col2 = p - row * 400;
    Tb[row * 420 + col2] = pack2(st[r].x, st[r].y);
  }
  {  // append h1 (no deg scale) as K-cols 800..831
    int row = tid >> 4, c2 = tid & 15;
    float2 hv = *(const float2*)&h1[(size_t)(n0 + row) * 32 + c2 * 2];
    Tb[row * 420 + 400 + c2] = pack2(hv.x, hv.y);
  }
  __syncthreads();
  // MFMA phase: wave wv computes nodes 0..15 x feats [wv*16, wv*16+16).
  int m = l & 15, quad = l >> 4;
  const char* abase = (const char*)T + m * 1680 + quad * 16;
  const unsigned short* bbase = W2T + (size_t)(wv * 16 + m) * 832 + quad * 8;
  float4v acc = {0.f, 0.f, 0.f, 0.f};
  for (int it = 0; it < 26; it++) {
    short8 af = *(const short8*)(abase + it * 64);
    short8 bf = *(const short8*)(bbase + it * 32);
    acc = __builtin_amdgcn_mfma_f32_16x16x32_bf16(af, bf, acc, 0, 0, 0);
  }
  int feat = wv * 16 + m;
  float bb = b2[feat];
#pragma unroll
  for (int r = 0; r < 4; r++) {
    int node = n0 + quad * 4 + r;
    h2[(size_t)node * 64 + feat] = eluf(acc[r] + bb);
  }
}

// Mean-pool h2 over each slice range -> gbuf[g][64]
__global__ __launch_bounds__(256) void pool(const float* __restrict__ h2,
                                            const int* __restrict__ slices,
                                            float* __restrict__ gbuf) {
  int g = blockIdx.x;
  int tid = threadIdx.x;
  int o = tid & 63, q = tid >> 6;
  int s0 = slices[g], s1 = slices[g + 1];
  float p = 0.f;
  for (int n = s0 + q; n < s1; n += 4) p += h2[(size_t)n * 64 + o];
  __shared__ float red[4][64];
  red[q][o] = p;
  __syncthreads();
  if (q == 0) {
    float s = red[0][o] + red[1][o] + red[2][o] + red[3][o];
    float cnt2 = (float)(s1 - s0);
    gbuf[g * 64 + o] = s / fmaxf(cnt2, 1.f);
  }
}

// FC(64->30) + log_softmax. One block (64 thr) per group; lanes 0..29 active.
__global__ __launch_bounds__(64) void fc_ls(const float* __restrict__ gbuf,
                                            const float* __restrict__ fcw,
                                            const float* __restrict__ fcb,
                                            float* __restrict__ out) {
  int g = blockIdx.x;
  int l = threadIdx.x;
  float logit = -INFINITY;
  if (l < 30) {
    float acc = fcb[l];
    for (int i = 0; i < 64; i++) acc += gbuf[g * 64 + i] * fcw[i * 30 + l];
    logit = acc;
  }
  float m = logit;
  for (int off = 16; off; off >>= 1) m = fmaxf(m, __shfl_xor(m, off, 32));
  float e = (l < 30) ? expf(logit - m) : 0.f;
  for (int off = 16; off; off >>= 1) e += __shfl_xor(e, off, 32);
  if (l < 30) out[g * 30 + l] = logit - m - logf(e);
}

extern "C" void kernel_launch(void* const* d_in, const int* in_sizes, int n_in,
                              void* d_out, int out_size, void* d_ws, size_t ws_size,
                              hipStream_t stream) {
  const float* x      = (const float*)d_in[0];
  const int*   ei     = (const int*)d_in[1];
  const float* pseudo = (const float*)d_in[2];
  const int*   slices = (const int*)d_in[3];
  const float* W1     = (const float*)d_in[4];
  const float* root1  = (const float*)d_in[5];
  const float* b1     = (const float*)d_in[6];
  const float* W2     = (const float*)d_in[7];
  const float* root2  = (const float*)d_in[8];
  const float* b2     = (const float*)d_in[9];
  const float* fcw    = (const float*)d_in[10];
  const float* fcb    = (const float*)d_in[11];
  float* out = (float*)d_out;

  char* ws = (char*)d_ws;
  int*   cnt    = (int*)ws;                                    // N ints
  int2*  bucket = (int2*)(cnt + N_NODES);                      // N*CAP int2 (26.2 MB)
  float* h1     = (float*)(bucket + (size_t)N_NODES * CAP);    // N*32
  float* h2     = h1 + (size_t)N_NODES * 32;                   // N*64
  float* gbuf   = h2 + (size_t)N_NODES * 64;                   // 64*64
  unsigned short* W2T = (unsigned short*)(gbuf + 64 * 64);     // 64*832 bf16

  hipMemsetAsync(cnt, 0, N_NODES * sizeof(int), stream);

  build_w2t<<<104, 256, 0, stream>>>(W2, root2, W2T);
  scatter_eid<<<N_EDGES / 256, 256, 0, stream>>>(ei, pseudo, cnt, bucket);
  fused_l1<<<N_NODES / L1_NODES, 256, 0, stream>>>(bucket, cnt, x, W1, root1, b1, h1);
  fused_l2<<<N_NODES / L2N, 256, 0, stream>>>(bucket, cnt, h1, W2T, b2, h2);
  pool<<<NB, 256, 0, stream>>>(h2, slices, gbuf);
  fc_ls<<<NB, 64, 0, stream>>>(gbuf, fcw, fcb, out);
}

// Round 8
// 319.461 us; speedup vs baseline: 2.8782x; 1.2839x over previous
//
#include <hip/hip_runtime.h>
#include <hip/hip_fp16.h>
#include <math.h>

#define N_NODES 51200
#define N_EDGES 819200
#define NB 64
#define CAP 64  // max in-degree; Binomial(E,1/N) mean 16, P(>=64) ~ 1e-19

typedef _Float16 half8 __attribute__((ext_vector_type(8)));
typedef __attribute__((ext_vector_type(4))) float float4v;

__device__ __forceinline__ float eluf(float x) {
  return x > 0.f ? x : expm1f(x);
}

// Build dst-CSR with fixed-capacity buckets; pack {src|K<<16, half2(f0,f1)}.
// cnt doubles as degree. (src < 65536 fits 16 bits.)
__global__ __launch_bounds__(256) void scatter_eid(const int* __restrict__ ei,
                                                   const float* __restrict__ pseudo,
                                                   int* __restrict__ cnt,
                                                   int2* __restrict__ bucket) {
  int e = blockIdx.x * 256 + threadIdx.x;
  int src = ei[e], dst = ei[N_EDGES + e];
  float v0 = pseudo[2 * e] * 4.f;
  float v1 = pseudo[2 * e + 1] * 4.f;
  int lo0 = min(max((int)floorf(v0), 0), 3);
  int lo1 = min(max((int)floorf(v1), 0), 3);
  float f0 = v0 - (float)lo0, f1 = v1 - (float)lo1;
  int K = lo0 * 5 + lo1;  // corners at K, K+1, K+5, K+6
  unsigned short u0 = __half_as_ushort(__float2half(f0));
  unsigned short u1 = __half_as_ushort(__float2half(f1));
  int w0 = src | (K << 16);
  int w1 = (int)((unsigned)u0 | ((unsigned)u1 << 16));
  int slot = atomicAdd(&cnt[dst], 1);
  if (slot < CAP) bucket[(size_t)dst * CAP + slot] = make_int2(w0, w1);
}

// x (N x 7 fp32) -> xh (N x 8 fp16, last = 0)
__global__ __launch_bounds__(256) void xcast(const float* __restrict__ x,
                                             __half* __restrict__ xh) {
  int idx = blockIdx.x * 256 + threadIdx.x;  // over N*8
  int n = idx >> 3, j = idx & 7;
  float v = (j < 7) ? x[n * 7 + j] : 0.f;
  xh[idx] = __float2half(v);
}

// W1T fp16 [32 feats][224]: k<200: cell=k>>3,f=k&7 (f<7) -> W1[cell][f][o];
// k in [200,207): root1[k-200][o]; else 0.
__global__ __launch_bounds__(256) void build_w1t(const float* __restrict__ W1,
                                                 const float* __restrict__ root1,
                                                 __half* __restrict__ W1T) {
  int idx = blockIdx.x * 256 + threadIdx.x;  // 32*224 = 7168
  int o = idx / 224, k = idx - o * 224;
  float v = 0.f;
  if (k < 200) {
    int cell = k >> 3, f = k & 7;
    if (f < 7) v = W1[(cell * 7 + f) * 32 + o];
  } else if (k < 207) {
    v = root1[(k - 200) * 32 + o];
  }
  W1T[idx] = __float2half(v);
}

// W2T fp16 [64 feats][832]: k<800 -> W2[k][o] (k = cell*32+i); else root2[k-800][o].
__global__ __launch_bounds__(256) void build_w2t(const float* __restrict__ W2,
                                                 const float* __restrict__ root2,
                                                 __half* __restrict__ W2T) {
  int idx = blockIdx.x * 256 + threadIdx.x;  // 64*832 = 53248
  int o = idx / 832, k = idx - o * 832;
  float v = (k < 800) ? W2[k * 64 + o] : root2[(k - 800) * 64 + o];
  W2T[idx] = __float2half(v);
}

// Layer 1 fused: T[32 nodes][224 halves] in LDS (race-free packed-half2 RMW,
// 4 nodes in parallel per wave), then MFMA f16:
// h1 = elu( ([T | deg*x] @ [W1;root1]T) * invdeg + b1 ), stored fp16.
#define L1N 32
__global__ __launch_bounds__(256) void fused_l1(const int2* __restrict__ bucket,
                                                const int* __restrict__ cnt,
                                                const unsigned* __restrict__ xh,   // N x 4 dwords
                                                const __half* __restrict__ W1T,
                                                const float* __restrict__ b1,
                                                unsigned short* __restrict__ h1h) {
  __shared__ unsigned T[L1N * 112];  // 32 rows x 224 halves = 14.3 KB
  __shared__ float invdeg_s[L1N];
  int tid = threadIdx.x;
  int n0 = blockIdx.x * L1N;
  for (int idx = tid; idx < L1N * 112; idx += 256) T[idx] = 0u;
  if (tid < L1N) invdeg_s[tid] = 1.f / fmaxf((float)cnt[n0 + tid], 1.f);
  __syncthreads();
  // append max(deg,1)*x at halves 200..207 (dwords 100..103); Phase A only
  // touches dwords < 100 -> no race.
  if (tid < 128) {
    int row = tid >> 2, p = tid & 3;
    int n = n0 + row;
    float dgc = fmaxf((float)cnt[n], 1.f);
    unsigned xv = xh[n * 4 + p];
    __half2 h = __hmul2(*(const __half2*)&xv, __float2half2_rn(dgc));
    T[row * 112 + 100 + p] = *(unsigned*)&h;
  }
  // Phase A: lane = slot(2b) | corner(2b) | pair(2b); 4 nodes per wave-iter.
  int wv = tid >> 6, l = tid & 63;
  int s = l >> 4, c = (l >> 2) & 3, p = l & 3;
  for (int g = 0; g < 2; g++) {
    int row = wv * 8 + g * 4 + s;
    int n = n0 + row;
    int dg = min(cnt[n], CAP);
    int dmax = dg;
    dmax = max(dmax, __shfl_xor(dmax, 16));
    dmax = max(dmax, __shfl_xor(dmax, 32));
    const int2* bk = bucket + (size_t)n * CAP;
    unsigned* Tr = &T[row * 112];
#pragma unroll 2
    for (int j = 0; j < dmax; j++) {
      if (j < dg) {
        int2 rec = bk[j];
        int src = rec.x & 0xFFFF, K = rec.x >> 16;
        unsigned pv = (unsigned)rec.y;
        float f0 = __half2float(__ushort_as_half((unsigned short)(pv & 0xFFFF)));
        float f1 = __half2float(__ushort_as_half((unsigned short)(pv >> 16)));
        float b0 = (c & 2) ? f0 : 1.f - f0;
        float bv = (c & 1) ? f1 : 1.f - f1;
        int Kc = K + (c >> 1) * 5 + (c & 1);
        unsigned hv = xh[src * 4 + p];
        __half2 prod = __hmul2(__float2half2_rn(b0 * bv), *(const __half2*)&hv);
        __half2* tp = (__half2*)&Tr[Kc * 4 + p];
        *tp = __hadd2(*tp, prod);
      }
    }
  }
  __syncthreads();
  // MFMA: wave wv -> (node tile mt = wv>>1, feat tile nt = wv&1), K=224 (7 iters).
  int m = l & 15, quad = l >> 4;
  int mt = wv >> 1, nt = wv & 1;
  const char* abase = (const char*)T + (mt * 16 + m) * 448 + quad * 16;
  const __half* bbase = W1T + (nt * 16 + m) * 224 + quad * 8;
  float4v acc = {0.f, 0.f, 0.f, 0.f};
#pragma unroll
  for (int it = 0; it < 7; it++) {
    half8 af = *(const half8*)(abase + it * 64);
    half8 bf = *(const half8*)(bbase + it * 32);
    acc = __builtin_amdgcn_mfma_f32_16x16x32_f16(af, bf, acc, 0, 0, 0);
  }
  int feat = nt * 16 + m;
  float bb = b1[feat];
#pragma unroll
  for (int r = 0; r < 4; r++) {
    int row = mt * 16 + quad * 4 + r;
    float v = eluf(acc[r] * invdeg_s[row] + bb);
    h1h[(size_t)(n0 + row) * 32 + feat] = __half_as_ushort(__float2half(v));
  }
}

// Layer 2 fused: T[16 nodes][840 halves] in LDS (race-free packed-half2 RMW),
// then MFMA f16: h2 = elu( ([T | deg*h1] @ [W2;root2]T) * invdeg + b2 ).
#define L2N 16
__global__ __launch_bounds__(256) void fused_l2(const int2* __restrict__ bucket,
                                                const int* __restrict__ cnt,
                                                const unsigned* __restrict__ h1hu,  // N x 16 dwords
                                                const __half* __restrict__ W2T,
                                                const float* __restrict__ b2,
                                                float* __restrict__ h2) {
  __shared__ unsigned T[L2N * 420];  // 16 rows x 840 halves = 26.9 KB
  __shared__ float invdeg_s[L2N];
  int tid = threadIdx.x;
  int n0 = blockIdx.x * L2N;
  for (int idx = tid; idx < L2N * 420; idx += 256) T[idx] = 0u;
  if (tid < L2N) invdeg_s[tid] = 1.f / fmaxf((float)cnt[n0 + tid], 1.f);
  __syncthreads();
  // append max(deg,1)*h1 at halves 800..831 (dwords 400..415); Phase A only
  // touches dwords < 400 -> no race.
  {
    int row = tid >> 4, p = tid & 15;
    int n = n0 + row;
    float dgc = fmaxf((float)cnt[n], 1.f);
    unsigned hv = h1hu[(size_t)n * 16 + p];
    __half2 h = __hmul2(*(const __half2*)&hv, __float2half2_rn(dgc));
    T[row * 420 + 400 + p] = *(unsigned*)&h;
  }
  // Phase A: wave wv -> nodes wv, wv+4, wv+8, wv+12; lane = corner(2b) x pair(4b).
  int wv = tid >> 6, l = tid & 63;
  int c = l >> 4, i = l & 15;
  for (int nn = wv; nn < L2N; nn += 4) {
    int n = n0 + nn;
    int dg = min(cnt[n], CAP);
    const int2* bk = bucket + (size_t)n * CAP;
    unsigned* Tr = &T[nn * 420];
#pragma unroll 2
    for (int j = 0; j < dg; j++) {
      int2 rec = bk[j];
      int src = rec.x & 0xFFFF, K = rec.x >> 16;
      unsigned pv = (unsigned)rec.y;
      float f0 = __half2float(__ushort_as_half((unsigned short)(pv & 0xFFFF)));
      float f1 = __half2float(__ushort_as_half((unsigned short)(pv >> 16)));
      float b0 = (c & 2) ? f0 : 1.f - f0;
      float bv = (c & 1) ? f1 : 1.f - f1;
      int Kc = K + (c >> 1) * 5 + (c & 1);
      unsigned hv = h1hu[(size_t)src * 16 + i];
      __half2 prod = __hmul2(__float2half2_rn(b0 * bv), *(const __half2*)&hv);
      __half2* tp = (__half2*)&Tr[Kc * 16 + i];
      *tp = __hadd2(*tp, prod);
    }
  }
  __syncthreads();
  // MFMA: wave wv -> feats [wv*16, wv*16+16), K=832 (26 iters).
  int m = l & 15, quad = l >> 4;
  const char* abase = (const char*)T + m * 1680 + quad * 16;
  const __half* bbase = W2T + (size_t)(wv * 16 + m) * 832 + quad * 8;
  float4v acc = {0.f, 0.f, 0.f, 0.f};
  for (int it = 0; it < 26; it++) {
    half8 af = *(const half8*)(abase + it * 64);
    half8 bf = *(const half8*)(bbase + it * 32);
    acc = __builtin_amdgcn_mfma_f32_16x16x32_f16(af, bf, acc, 0, 0, 0);
  }
  int feat = wv * 16 + m;
  float bb = b2[feat];
#pragma unroll
  for (int r = 0; r < 4; r++) {
    int node = quad * 4 + r;
    h2[(size_t)(n0 + node) * 64 + feat] = eluf(acc[r] * invdeg_s[node] + bb);
  }
}

// Mean-pool h2 over each slice range -> gbuf[g][64]
__global__ __launch_bounds__(256) void pool(const float* __restrict__ h2,
                                            const int* __restrict__ slices,
                                            float* __restrict__ gbuf) {
  int g = blockIdx.x;
  int tid = threadIdx.x;
  int o = tid & 63, q = tid >> 6;
  int s0 = slices[g], s1 = slices[g + 1];
  float p = 0.f;
  for (int n = s0 + q; n < s1; n += 4) p += h2[(size_t)n * 64 + o];
  __shared__ float red[4][64];
  red[q][o] = p;
  __syncthreads();
  if (q == 0) {
    float s = red[0][o] + red[1][o] + red[2][o] + red[3][o];
    float cnt2 = (float)(s1 - s0);
    gbuf[g * 64 + o] = s / fmaxf(cnt2, 1.f);
  }
}

// FC(64->30) + log_softmax. One block (64 thr) per group; lanes 0..29 active.
__global__ __launch_bounds__(64) void fc_ls(const float* __restrict__ gbuf,
                                            const float* __restrict__ fcw,
                                            const float* __restrict__ fcb,
                                            float* __restrict__ out) {
  int g = blockIdx.x;
  int l = threadIdx.x;
  float logit = -INFINITY;
  if (l < 30) {
    float acc = fcb[l];
    for (int i = 0; i < 64; i++) acc += gbuf[g * 64 + i] * fcw[i * 30 + l];
    logit = acc;
  }
  float m = logit;
  for (int off = 16; off; off >>= 1) m = fmaxf(m, __shfl_xor(m, off, 32));
  float e = (l < 30) ? expf(logit - m) : 0.f;
  for (int off = 16; off; off >>= 1) e += __shfl_xor(e, off, 32);
  if (l < 30) out[g * 30 + l] = logit - m - logf(e);
}

extern "C" void kernel_launch(void* const* d_in, const int* in_sizes, int n_in,
                              void* d_out, int out_size, void* d_ws, size_t ws_size,
                              hipStream_t stream) {
  const float* x      = (const float*)d_in[0];
  const int*   ei     = (const int*)d_in[1];
  const float* pseudo = (const float*)d_in[2];
  const int*   slices = (const int*)d_in[3];
  const float* W1     = (const float*)d_in[4];
  const float* root1  = (const float*)d_in[5];
  const float* b1     = (const float*)d_in[6];
  const float* W2     = (const float*)d_in[7];
  const float* root2  = (const float*)d_in[8];
  const float* b2     = (const float*)d_in[9];
  const float* fcw    = (const float*)d_in[10];
  const float* fcb    = (const float*)d_in[11];
  float* out = (float*)d_out;

  char* ws = (char*)d_ws;
  int*      cnt    = (int*)ws;                                    // N ints
  int2*     bucket = (int2*)(cnt + N_NODES);                      // N*CAP int2 (26.2 MB)
  unsigned* h1h    = (unsigned*)(bucket + (size_t)N_NODES * CAP); // N*16 dwords (fp16 h1)
  float*    h2     = (float*)(h1h + (size_t)N_NODES * 16);        // N*64 fp32
  float*    gbuf   = h2 + (size_t)N_NODES * 64;                   // 64*64
  unsigned* xh     = (unsigned*)(gbuf + 64 * 64);                 // N*4 dwords (fp16 x)
  __half*   W1T    = (__half*)(xh + (size_t)N_NODES * 4);         // 32*224
  __half*   W2T    = W1T + 32 * 224;                              // 64*832

  hipMemsetAsync(cnt, 0, N_NODES * sizeof(int), stream);

  xcast<<<N_NODES * 8 / 256, 256, 0, stream>>>(x, (__half*)xh);
  build_w1t<<<28, 256, 0, stream>>>(W1, root1, W1T);
  build_w2t<<<208, 256, 0, stream>>>(W2, root2, W2T);
  scatter_eid<<<N_EDGES / 256, 256, 0, stream>>>(ei, pseudo, cnt, bucket);
  fused_l1<<<N_NODES / L1N, 256, 0, stream>>>(bucket, cnt, xh, W1T, b1,
                                              (unsigned short*)h1h);
  fused_l2<<<N_NODES / L2N, 256, 0, stream>>>(bucket, cnt, h1h, W2T, b2, h2);
  pool<<<NB, 256, 0, stream>>>(h2, slices, gbuf);
  fc_ls<<<NB, 64, 0, stream>>>(gbuf, fcw, fcb, out);
}

// Round 9
// 285.621 us; speedup vs baseline: 3.2192x; 1.1185x over previous
//
#include <hip/hip_runtime.h>
#include <hip/hip_fp16.h>
#include <math.h>

#define N_NODES 51200
#define N_EDGES 819200
#define NB 64
#define CAP 64  // max in-degree; Binomial(E,1/N) mean 16, P(>=64) ~ 1e-19

typedef _Float16 half8 __attribute__((ext_vector_type(8)));
typedef __attribute__((ext_vector_type(4))) float float4v;

__device__ __forceinline__ float eluf(float x) {
  return x > 0.f ? x : expm1f(x);
}

// Decode packed edge record for corner c -> basis weight + cell index.
__device__ __forceinline__ void dec(int2 rec, int c, float& basf, int& Kc) {
  int K = rec.x >> 16;
  unsigned pv = (unsigned)rec.y;
  float f0 = __half2float(__ushort_as_half((unsigned short)(pv & 0xFFFF)));
  float f1 = __half2float(__ushort_as_half((unsigned short)(pv >> 16)));
  float b0 = (c & 2) ? f0 : 1.f - f0;
  float bv = (c & 1) ? f1 : 1.f - f1;
  Kc = K + (c >> 1) * 5 + (c & 1);
  basf = b0 * bv;
}

// Build dst-CSR with fixed-capacity buckets; pack {src|K<<16, half2(f0,f1)}.
// cnt doubles as degree. (src < 65536 fits 16 bits.)
__global__ __launch_bounds__(256) void scatter_eid(const int* __restrict__ ei,
                                                   const float* __restrict__ pseudo,
                                                   int* __restrict__ cnt,
                                                   int2* __restrict__ bucket) {
  int e = blockIdx.x * 256 + threadIdx.x;
  int src = ei[e], dst = ei[N_EDGES + e];
  float v0 = pseudo[2 * e] * 4.f;
  float v1 = pseudo[2 * e + 1] * 4.f;
  int lo0 = min(max((int)floorf(v0), 0), 3);
  int lo1 = min(max((int)floorf(v1), 0), 3);
  float f0 = v0 - (float)lo0, f1 = v1 - (float)lo1;
  int K = lo0 * 5 + lo1;  // corners at K, K+1, K+5, K+6
  unsigned short u0 = __half_as_ushort(__float2half(f0));
  unsigned short u1 = __half_as_ushort(__float2half(f1));
  int w0 = src | (K << 16);
  int w1 = (int)((unsigned)u0 | ((unsigned)u1 << 16));
  int slot = atomicAdd(&cnt[dst], 1);
  if (slot < CAP) bucket[(size_t)dst * CAP + slot] = make_int2(w0, w1);
}

// x (N x 7 fp32) -> xh (N x 8 fp16, last = 0)
__global__ __launch_bounds__(256) void xcast(const float* __restrict__ x,
                                             __half* __restrict__ xh) {
  int idx = blockIdx.x * 256 + threadIdx.x;  // over N*8
  int n = idx >> 3, j = idx & 7;
  float v = (j < 7) ? x[n * 7 + j] : 0.f;
  xh[idx] = __float2half(v);
}

// W1T fp16 [32 feats][224]: k<200: cell=k>>3,f=k&7 (f<7) -> W1[cell][f][o];
// k in [200,207): root1[k-200][o]; else 0.
__global__ __launch_bounds__(256) void build_w1t(const float* __restrict__ W1,
                                                 const float* __restrict__ root1,
                                                 __half* __restrict__ W1T) {
  int idx = blockIdx.x * 256 + threadIdx.x;  // 32*224 = 7168
  int o = idx / 224, k = idx - o * 224;
  float v = 0.f;
  if (k < 200) {
    int cell = k >> 3, f = k & 7;
    if (f < 7) v = W1[(cell * 7 + f) * 32 + o];
  } else if (k < 207) {
    v = root1[(k - 200) * 32 + o];
  }
  W1T[idx] = __float2half(v);
}

// W2T fp16 [64 feats][832]: k<800 -> W2[k][o] (k = cell*32+i); else root2[k-800][o].
__global__ __launch_bounds__(256) void build_w2t(const float* __restrict__ W2,
                                                 const float* __restrict__ root2,
                                                 __half* __restrict__ W2T) {
  int idx = blockIdx.x * 256 + threadIdx.x;  // 64*832 = 53248
  int o = idx / 832, k = idx - o * 832;
  float v = (k < 800) ? W2[k * 64 + o] : root2[(k - 800) * 64 + o];
  W2T[idx] = __float2half(v);
}

// Layer 1 fused: T[16 nodes][224 halves] in LDS; Phase A processes the wave's
// 4 nodes in PARALLEL (lane = slot|corner|pair -> 4 independent chains), then
// MFMA f16: h1 = elu( ([T | deg*x] @ [W1;root1]T) * invdeg + b1 ), fp16 out.
#define L1N 16
__global__ __launch_bounds__(256) void fused_l1(const int2* __restrict__ bucket,
                                                const int* __restrict__ cnt,
                                                const unsigned* __restrict__ xh,   // N x 4 dwords
                                                const __half* __restrict__ W1T,
                                                const float* __restrict__ b1,
                                                unsigned short* __restrict__ h1h) {
  __shared__ unsigned T[L1N * 112];  // 16 rows x 224 halves = 7.2 KB
  __shared__ float invdeg_s[L1N];
  int tid = threadIdx.x;
  int n0 = blockIdx.x * L1N;
  for (int idx = tid; idx < L1N * 112; idx += 256) T[idx] = 0u;
  if (tid < L1N) invdeg_s[tid] = 1.f / fmaxf((float)cnt[n0 + tid], 1.f);
  __syncthreads();
  // append max(deg,1)*x at halves 200..207 (dwords 100..103); Phase A only
  // touches dwords < 100 -> no race.
  if (tid < L1N * 4) {
    int row = tid >> 2, p = tid & 3;
    int n = n0 + row;
    float dgc = fmaxf((float)cnt[n], 1.f);
    unsigned xv = xh[n * 4 + p];
    __half2 h = __hmul2(*(const __half2*)&xv, __float2half2_rn(dgc));
    T[row * 112 + 100 + p] = *(unsigned*)&h;
  }
  // Phase A: lane = slot(2b) | corner(2b) | pair(2b); 4 nodes per wave in
  // parallel (distinct T rows -> race-free), manual 2x pipeline on edges.
  int wv = tid >> 6, l = tid & 63;
  int slot = l >> 4, c = (l >> 2) & 3, p = l & 3;
  int nn = wv * 4 + slot;
  int n = n0 + nn;
  int dg = min(cnt[n], CAP);
  int dmax = dg;
  dmax = max(dmax, __shfl_xor(dmax, 16));
  dmax = max(dmax, __shfl_xor(dmax, 32));
  const int2* bk = bucket + (size_t)n * CAP;
  unsigned* Tr = &T[nn * 112];
  for (int j = 0; j < dmax; j += 2) {
    bool a0 = j < dg, a1 = j + 1 < dg;
    int2 r0 = bk[j];
    int2 r1 = bk[j + 1];
    int s0 = r0.x & 0xFFFF, s1 = r1.x & 0xFFFF;
    unsigned xv0 = a0 ? xh[s0 * 4 + p] : 0u;
    unsigned xv1 = a1 ? xh[s1 * 4 + p] : 0u;
    if (a0) {
      float bf; int Kc; dec(r0, c, bf, Kc);
      __half2* tp = (__half2*)&Tr[Kc * 4 + p];
      *tp = __hfma2(__float2half2_rn(bf), *(const __half2*)&xv0, *tp);
    }
    if (a1) {
      float bf; int Kc; dec(r1, c, bf, Kc);
      __half2* tp = (__half2*)&Tr[Kc * 4 + p];
      *tp = __hfma2(__float2half2_rn(bf), *(const __half2*)&xv1, *tp);
    }
  }
  __syncthreads();
  // MFMA: waves 0,1 -> feat tiles 0,1; M=16 nodes, K=224 (7 iters).
  if (wv < 2) {
    int m = l & 15, quad = l >> 4;
    const char* abase = (const char*)T + m * 448 + quad * 16;
    const __half* bbase = W1T + (wv * 16 + m) * 224 + quad * 8;
    float4v acc = {0.f, 0.f, 0.f, 0.f};
#pragma unroll
    for (int it = 0; it < 7; it++) {
      half8 af = *(const half8*)(abase + it * 64);
      half8 bf = *(const half8*)(bbase + it * 32);
      acc = __builtin_amdgcn_mfma_f32_16x16x32_f16(af, bf, acc, 0, 0, 0);
    }
    int feat = wv * 16 + m;
    float bb = b1[feat];
#pragma unroll
    for (int r = 0; r < 4; r++) {
      int row = quad * 4 + r;
      float v = eluf(acc[r] * invdeg_s[row] + bb);
      h1h[(size_t)(n0 + row) * 32 + feat] = __half_as_ushort(__float2half(v));
    }
  }
}

// Layer 2 fused: T[16 nodes][840 halves] in LDS; Phase A processes the wave's
// 4 nodes in PARALLEL (lane = slot|corner|quarter; 16B b128 RMW per lane),
// then MFMA f16: h2 = elu( ([T | deg*h1] @ [W2;root2]T) * invdeg + b2 ).
#define L2N 16
__global__ __launch_bounds__(256) void fused_l2(const int2* __restrict__ bucket,
                                                const int* __restrict__ cnt,
                                                const unsigned* __restrict__ h1hu,  // N x 16 dwords
                                                const __half* __restrict__ W2T,
                                                const float* __restrict__ b2,
                                                float* __restrict__ h2) {
  __shared__ unsigned T[L2N * 420];  // 16 rows x 840 halves = 26.9 KB
  __shared__ float invdeg_s[L2N];
  int tid = threadIdx.x;
  int n0 = blockIdx.x * L2N;
  for (int idx = tid; idx < L2N * 420; idx += 256) T[idx] = 0u;
  if (tid < L2N) invdeg_s[tid] = 1.f / fmaxf((float)cnt[n0 + tid], 1.f);
  __syncthreads();
  // append max(deg,1)*h1 at halves 800..831 (dwords 400..415); Phase A only
  // touches dwords < 400 -> no race.
  {
    int row = tid >> 4, p = tid & 15;
    int n = n0 + row;
    float dgc = fmaxf((float)cnt[n], 1.f);
    unsigned hv = h1hu[(size_t)n * 16 + p];
    __half2 h = __hmul2(*(const __half2*)&hv, __float2half2_rn(dgc));
    T[row * 420 + 400 + p] = *(unsigned*)&h;
  }
  // Phase A: lane = slot(2b) | corner(2b) | quarter(2b); 4 nodes per wave in
  // parallel, 16B LDS RMW per lane, manual 2x pipeline on edges.
  int wv = tid >> 6, l = tid & 63;
  int slot = l >> 4, c = (l >> 2) & 3, q = l & 3;
  int nn = wv * 4 + slot;
  int n = n0 + nn;
  int dg = min(cnt[n], CAP);
  int dmax = dg;
  dmax = max(dmax, __shfl_xor(dmax, 16));
  dmax = max(dmax, __shfl_xor(dmax, 32));
  const int2* bk = bucket + (size_t)n * CAP;
  unsigned* Tr = &T[nn * 420];
  const unsigned* h1q = h1hu + q * 4;
  for (int j = 0; j < dmax; j += 2) {
    bool a0 = j < dg, a1 = j + 1 < dg;
    int2 r0 = bk[j];
    int2 r1 = bk[j + 1];
    int s0 = r0.x & 0xFFFF, s1 = r1.x & 0xFFFF;
    int4 hv0 = a0 ? *(const int4*)(h1q + (size_t)s0 * 16) : make_int4(0, 0, 0, 0);
    int4 hv1 = a1 ? *(const int4*)(h1q + (size_t)s1 * 16) : make_int4(0, 0, 0, 0);
    if (a0) {
      float bf; int Kc; dec(r0, c, bf, Kc);
      __half2 bas = __float2half2_rn(bf);
      __half2* tp = (__half2*)&Tr[Kc * 16 + q * 4];
      const __half2* h = (const __half2*)&hv0;
      __half2 t0 = tp[0], t1 = tp[1], t2 = tp[2], t3 = tp[3];
      t0 = __hfma2(bas, h[0], t0);
      t1 = __hfma2(bas, h[1], t1);
      t2 = __hfma2(bas, h[2], t2);
      t3 = __hfma2(bas, h[3], t3);
      tp[0] = t0; tp[1] = t1; tp[2] = t2; tp[3] = t3;
    }
    if (a1) {
      float bf; int Kc; dec(r1, c, bf, Kc);
      __half2 bas = __float2half2_rn(bf);
      __half2* tp = (__half2*)&Tr[Kc * 16 + q * 4];
      const __half2* h = (const __half2*)&hv1;
      __half2 t0 = tp[0], t1 = tp[1], t2 = tp[2], t3 = tp[3];
      t0 = __hfma2(bas, h[0], t0);
      t1 = __hfma2(bas, h[1], t1);
      t2 = __hfma2(bas, h[2], t2);
      t3 = __hfma2(bas, h[3], t3);
      tp[0] = t0; tp[1] = t1; tp[2] = t2; tp[3] = t3;
    }
  }
  __syncthreads();
  // MFMA: wave wv -> feats [wv*16, wv*16+16), K=832 (26 iters).
  int m = l & 15, quad = l >> 4;
  const char* abase = (const char*)T + m * 1680 + quad * 16;
  const __half* bbase = W2T + (size_t)(wv * 16 + m) * 832 + quad * 8;
  float4v acc = {0.f, 0.f, 0.f, 0.f};
  for (int it = 0; it < 26; it++) {
    half8 af = *(const half8*)(abase + it * 64);
    half8 bf = *(const half8*)(bbase + it * 32);
    acc = __builtin_amdgcn_mfma_f32_16x16x32_f16(af, bf, acc, 0, 0, 0);
  }
  int feat = wv * 16 + m;
  float bb = b2[feat];
#pragma unroll
  for (int r = 0; r < 4; r++) {
    int node = quad * 4 + r;
    h2[(size_t)(n0 + node) * 64 + feat] = eluf(acc[r] * invdeg_s[node] + bb);
  }
}

// Mean-pool h2 over each slice range -> gbuf[g][64]
__global__ __launch_bounds__(256) void pool(const float* __restrict__ h2,
                                            const int* __restrict__ slices,
                                            float* __restrict__ gbuf) {
  int g = blockIdx.x;
  int tid = threadIdx.x;
  int o = tid & 63, q = tid >> 6;
  int s0 = slices[g], s1 = slices[g + 1];
  float p = 0.f;
  for (int n = s0 + q; n < s1; n += 4) p += h2[(size_t)n * 64 + o];
  __shared__ float red[4][64];
  red[q][o] = p;
  __syncthreads();
  if (q == 0) {
    float s = red[0][o] + red[1][o] + red[2][o] + red[3][o];
    float cnt2 = (float)(s1 - s0);
    gbuf[g * 64 + o] = s / fmaxf(cnt2, 1.f);
  }
}

// FC(64->30) + log_softmax. One block (64 thr) per group; lanes 0..29 active.
__global__ __launch_bounds__(64) void fc_ls(const float* __restrict__ gbuf,
                                            const float* __restrict__ fcw,
                                            const float* __restrict__ fcb,
                                            float* __restrict__ out) {
  int g = blockIdx.x;
  int l = threadIdx.x;
  float logit = -INFINITY;
  if (l < 30) {
    float acc = fcb[l];
    for (int i = 0; i < 64; i++) acc += gbuf[g * 64 + i] * fcw[i * 30 + l];
    logit = acc;
  }
  float m = logit;
  for (int off = 16; off; off >>= 1) m = fmaxf(m, __shfl_xor(m, off, 32));
  float e = (l < 30) ? expf(logit - m) : 0.f;
  for (int off = 16; off; off >>= 1) e += __shfl_xor(e, off, 32);
  if (l < 30) out[g * 30 + l] = logit - m - logf(e);
}

extern "C" void kernel_launch(void* const* d_in, const int* in_sizes, int n_in,
                              void* d_out, int out_size, void* d_ws, size_t ws_size,
                              hipStream_t stream) {
  const float* x      = (const float*)d_in[0];
  const int*   ei     = (const int*)d_in[1];
  const float* pseudo = (const float*)d_in[2];
  const int*   slices = (const int*)d_in[3];
  const float* W1     = (const float*)d_in[4];
  const float* root1  = (const float*)d_in[5];
  const float* b1     = (const float*)d_in[6];
  const float* W2     = (const float*)d_in[7];
  const float* root2  = (const float*)d_in[8];
  const float* b2     = (const float*)d_in[9];
  const float* fcw    = (const float*)d_in[10];
  const float* fcb    = (const float*)d_in[11];
  float* out = (float*)d_out;

  char* ws = (char*)d_ws;
  int*      cnt    = (int*)ws;                                    // N ints
  int2*     bucket = (int2*)(cnt + N_NODES);                      // N*CAP int2 (26.2 MB)
  unsigned* h1h    = (unsigned*)(bucket + (size_t)N_NODES * CAP); // N*16 dwords (fp16 h1)
  float*    h2     = (float*)(h1h + (size_t)N_NODES * 16);        // N*64 fp32
  float*    gbuf   = h2 + (size_t)N_NODES * 64;                   // 64*64
  unsigned* xh     = (unsigned*)(gbuf + 64 * 64);                 // N*4 dwords (fp16 x)
  __half*   W1T    = (__half*)(xh + (size_t)N_NODES * 4);         // 32*224
  __half*   W2T    = W1T + 32 * 224;                              // 64*832

  hipMemsetAsync(cnt, 0, N_NODES * sizeof(int), stream);

  xcast<<<N_NODES * 8 / 256, 256, 0, stream>>>(x, (__half*)xh);
  build_w1t<<<28, 256, 0, stream>>>(W1, root1, W1T);
  build_w2t<<<208, 256, 0, stream>>>(W2, root2, W2T);
  scatter_eid<<<N_EDGES / 256, 256, 0, stream>>>(ei, pseudo, cnt, bucket);
  fused_l1<<<N_NODES / L1N, 256, 0, stream>>>(bucket, cnt, xh, W1T, b1,
                                              (unsigned short*)h1h);
  fused_l2<<<N_NODES / L2N, 256, 0, stream>>>(bucket, cnt, h1h, W2T, b2, h2);
  pool<<<NB, 256, 0, stream>>>(h2, slices, gbuf);
  fc_ls<<<NB, 64, 0, stream>>>(gbuf, fcw, fcb, out);
}

// Round 10
// 237.935 us; speedup vs baseline: 3.8643x; 1.2004x over previous
//
#include <hip/hip_runtime.h>
#include <hip/hip_fp16.h>
#include <math.h>

#define N_NODES 51200
#define N_EDGES 819200
#define NB 64
#define CAP 64  // max in-degree; Binomial(E,1/N) mean 16, P(>=64) ~ 1e-19

typedef _Float16 half8 __attribute__((ext_vector_type(8)));
typedef __attribute__((ext_vector_type(4))) float float4v;

__device__ __forceinline__ float eluf(float x) {
  return x > 0.f ? x : expm1f(x);
}

// Decode packed edge record {w0 = src|K<<16, w1 = half2(f0,f1)} for corner c.
__device__ __forceinline__ void dec2(int w0, int w1, int c, float& basf, int& Kc) {
  int K = w0 >> 16;  // src < 65536, K <= 18 -> w0 >= 0
  float f0 = __half2float(__ushort_as_half((unsigned short)(w1 & 0xFFFF)));
  float f1 = __half2float(__ushort_as_half((unsigned short)(((unsigned)w1) >> 16)));
  float b0 = (c & 2) ? f0 : 1.f - f0;
  float bv = (c & 1) ? f1 : 1.f - f1;
  Kc = K + (c >> 1) * 5 + (c & 1);
  basf = b0 * bv;
}

// 16B LDS RMW: T row chunk [Kc*16 + q*4 .. +3] (+4 half2 fma).
__device__ __forceinline__ void rmw16(unsigned* Tr, int Kc, int q, float bf, int4 hv) {
  __half2 bas = __float2half2_rn(bf);
  __half2* tp = (__half2*)&Tr[Kc * 16 + q * 4];
  const __half2* h = (const __half2*)&hv;
  __half2 t0 = tp[0], t1 = tp[1], t2 = tp[2], t3 = tp[3];
  tp[0] = __hfma2(bas, h[0], t0);
  tp[1] = __hfma2(bas, h[1], t1);
  tp[2] = __hfma2(bas, h[2], t2);
  tp[3] = __hfma2(bas, h[3], t3);
}

// Prep: xcast (N x 7 fp32 -> N x 8 fp16) | W1T | W2T | zero gbuf. Grid 1852.
__global__ __launch_bounds__(256) void prep(const float* __restrict__ x,
                                            const float* __restrict__ W1,
                                            const float* __restrict__ root1,
                                            const float* __restrict__ W2,
                                            const float* __restrict__ root2,
                                            __half* __restrict__ xh,
                                            __half* __restrict__ W1T,
                                            __half* __restrict__ W2T,
                                            float* __restrict__ gbuf) {
  int b = blockIdx.x, tid = threadIdx.x;
  if (b < 1600) {                       // xcast: N*8 = 409600
    int idx = b * 256 + tid;
    int n = idx >> 3, j = idx & 7;
    xh[idx] = __float2half((j < 7) ? x[n * 7 + j] : 0.f);
  } else if (b < 1628) {                // W1T: 32 feats x 224 = 7168
    int idx = (b - 1600) * 256 + tid;
    int o = idx / 224, k = idx - o * 224;
    float v = 0.f;
    if (k < 200) {
      int cell = k >> 3, f = k & 7;
      if (f < 7) v = W1[(cell * 7 + f) * 32 + o];
    } else if (k < 207) {
      v = root1[(k - 200) * 32 + o];
    }
    W1T[idx] = __float2half(v);
  } else if (b < 1836) {                // W2T: 64 feats x 832 = 53248
    int idx = (b - 1628) * 256 + tid;
    int o = idx / 832, k = idx - o * 832;
    float v = (k < 800) ? W2[k * 64 + o] : root2[(k - 800) * 64 + o];
    W2T[idx] = __float2half(v);
  } else {                              // zero gbuf: 64*64 = 4096
    int idx = (b - 1836) * 256 + tid;
    gbuf[idx] = 0.f;
  }
}

// Build dst-CSR with fixed-capacity buckets; 4 edges per thread (4 independent
// atomic chains in flight). cnt doubles as degree.
__global__ __launch_bounds__(256) void scatter_eid(const int* __restrict__ ei,
                                                   const float* __restrict__ pseudo,
                                                   int* __restrict__ cnt,
                                                   int2* __restrict__ bucket) {
  int base = blockIdx.x * 1024 + threadIdx.x;
#pragma unroll
  for (int u = 0; u < 4; u++) {
    int e = base + u * 256;
    int src = ei[e], dst = ei[N_EDGES + e];
    float v0 = pseudo[2 * e] * 4.f;
    float v1 = pseudo[2 * e + 1] * 4.f;
    int lo0 = min(max((int)floorf(v0), 0), 3);
    int lo1 = min(max((int)floorf(v1), 0), 3);
    float f0 = v0 - (float)lo0, f1 = v1 - (float)lo1;
    int K = lo0 * 5 + lo1;  // corners at K, K+1, K+5, K+6
    unsigned short u0 = __half_as_ushort(__float2half(f0));
    unsigned short u1 = __half_as_ushort(__float2half(f1));
    int w0 = src | (K << 16);
    int w1 = (int)((unsigned)u0 | ((unsigned)u1 << 16));
    int slot = atomicAdd(&cnt[dst], 1);
    if (slot < CAP) bucket[(size_t)dst * CAP + slot] = make_int2(w0, w1);
  }
}

// Layer 1 fused: T[16 nodes][224 halves] in LDS; Phase A: 4 nodes in parallel
// per wave (lane = slot|corner|pair), 4x-unrolled edge loop; then MFMA f16:
// h1 = elu( ([T | deg*x] @ [W1;root1]T) * invdeg + b1 ), fp16 out.
#define L1N 16
__global__ __launch_bounds__(256) void fused_l1(const int2* __restrict__ bucket,
                                                const int* __restrict__ cnt,
                                                const unsigned* __restrict__ xh,   // N x 4 dwords
                                                const __half* __restrict__ W1T,
                                                const float* __restrict__ b1,
                                                unsigned short* __restrict__ h1h) {
  __shared__ unsigned T[L1N * 112];  // 7.2 KB
  __shared__ float invdeg_s[L1N];
  int tid = threadIdx.x;
  int n0 = blockIdx.x * L1N;
  for (int idx = tid; idx < L1N * 112; idx += 256) T[idx] = 0u;
  if (tid < L1N) invdeg_s[tid] = 1.f / fmaxf((float)cnt[n0 + tid], 1.f);
  __syncthreads();
  // append max(deg,1)*x at dwords 100..103 (Phase A touches dwords < 100).
  if (tid < L1N * 4) {
    int row = tid >> 2, p = tid & 3;
    int n = n0 + row;
    float dgc = fmaxf((float)cnt[n], 1.f);
    unsigned xv = xh[n * 4 + p];
    __half2 h = __hmul2(*(const __half2*)&xv, __float2half2_rn(dgc));
    T[row * 112 + 100 + p] = *(unsigned*)&h;
  }
  int wv = tid >> 6, l = tid & 63;
  int slot = l >> 4, c = (l >> 2) & 3, p = l & 3;
  int nn = wv * 4 + slot;
  int n = n0 + nn;
  int dg = min(cnt[n], CAP);
  int dmax = dg;
  dmax = max(dmax, __shfl_xor(dmax, 16));
  dmax = max(dmax, __shfl_xor(dmax, 32));
  const int2* bk = bucket + (size_t)n * CAP;
  unsigned* Tr = &T[nn * 112];
  for (int j = 0; j < dmax; j += 4) {
    int4 ra = *(const int4*)(bk + j);      // records j, j+1
    int4 rb = *(const int4*)(bk + j + 2);  // records j+2, j+3
    bool a0 = j < dg, a1 = j + 1 < dg, a2 = j + 2 < dg, a3 = j + 3 < dg;
    unsigned xv0 = a0 ? xh[(ra.x & 0xFFFF) * 4 + p] : 0u;
    unsigned xv1 = a1 ? xh[(ra.z & 0xFFFF) * 4 + p] : 0u;
    unsigned xv2 = a2 ? xh[(rb.x & 0xFFFF) * 4 + p] : 0u;
    unsigned xv3 = a3 ? xh[(rb.z & 0xFFFF) * 4 + p] : 0u;
    float bf; int Kc;
    if (a0) { dec2(ra.x, ra.y, c, bf, Kc);
      __half2* tp = (__half2*)&Tr[Kc * 4 + p];
      *tp = __hfma2(__float2half2_rn(bf), *(const __half2*)&xv0, *tp); }
    if (a1) { dec2(ra.z, ra.w, c, bf, Kc);
      __half2* tp = (__half2*)&Tr[Kc * 4 + p];
      *tp = __hfma2(__float2half2_rn(bf), *(const __half2*)&xv1, *tp); }
    if (a2) { dec2(rb.x, rb.y, c, bf, Kc);
      __half2* tp = (__half2*)&Tr[Kc * 4 + p];
      *tp = __hfma2(__float2half2_rn(bf), *(const __half2*)&xv2, *tp); }
    if (a3) { dec2(rb.z, rb.w, c, bf, Kc);
      __half2* tp = (__half2*)&Tr[Kc * 4 + p];
      *tp = __hfma2(__float2half2_rn(bf), *(const __half2*)&xv3, *tp); }
  }
  __syncthreads();
  // MFMA: waves 0,1 -> feat tiles 0,1; M=16 nodes, K=224 (7 iters).
  if (wv < 2) {
    int m = l & 15, quad = l >> 4;
    const char* abase = (const char*)T + m * 448 + quad * 16;
    const __half* bbase = W1T + (wv * 16 + m) * 224 + quad * 8;
    float4v acc = {0.f, 0.f, 0.f, 0.f};
#pragma unroll
    for (int it = 0; it < 7; it++) {
      half8 af = *(const half8*)(abase + it * 64);
      half8 bf = *(const half8*)(bbase + it * 32);
      acc = __builtin_amdgcn_mfma_f32_16x16x32_f16(af, bf, acc, 0, 0, 0);
    }
    int feat = wv * 16 + m;
    float bb = b1[feat];
#pragma unroll
    for (int r = 0; r < 4; r++) {
      int row = quad * 4 + r;
      float v = eluf(acc[r] * invdeg_s[row] + bb);
      h1h[(size_t)(n0 + row) * 32 + feat] = __half_as_ushort(__float2half(v));
    }
  }
}

// Layer 2 fused: T[16 nodes][840 halves] in LDS; Phase A: 4 nodes in parallel
// per wave (lane = slot|corner|quarter, 16B b128 RMW), 4x-unrolled edge loop;
// MFMA f16 epilogue computes elu rows AND pool-reduces them straight into
// gbuf via one atomicAdd per (block, feat). h2 is never materialized.
#define L2N 16
__global__ __launch_bounds__(256) void fused_l2(const int2* __restrict__ bucket,
                                                const int* __restrict__ cnt,
                                                const unsigned* __restrict__ h1hu,  // N x 16 dwords
                                                const __half* __restrict__ W2T,
                                                const float* __restrict__ b2,
                                                float* __restrict__ gbuf) {
  __shared__ unsigned T[L2N * 420];  // 26.9 KB
  __shared__ float invdeg_s[L2N];
  int tid = threadIdx.x;
  int n0 = blockIdx.x * L2N;
  for (int idx = tid; idx < L2N * 420; idx += 256) T[idx] = 0u;
  if (tid < L2N) invdeg_s[tid] = 1.f / fmaxf((float)cnt[n0 + tid], 1.f);
  __syncthreads();
  // append max(deg,1)*h1 at dwords 400..415 (Phase A touches dwords < 400).
  {
    int row = tid >> 4, p = tid & 15;
    int n = n0 + row;
    float dgc = fmaxf((float)cnt[n], 1.f);
    unsigned hv = h1hu[(size_t)n * 16 + p];
    __half2 h = __hmul2(*(const __half2*)&hv, __float2half2_rn(dgc));
    T[row * 420 + 400 + p] = *(unsigned*)&h;
  }
  int wv = tid >> 6, l = tid & 63;
  int slot = l >> 4, c = (l >> 2) & 3, q = l & 3;
  int nn = wv * 4 + slot;
  int n = n0 + nn;
  int dg = min(cnt[n], CAP);
  int dmax = dg;
  dmax = max(dmax, __shfl_xor(dmax, 16));
  dmax = max(dmax, __shfl_xor(dmax, 32));
  const int2* bk = bucket + (size_t)n * CAP;
  unsigned* Tr = &T[nn * 420];
  const unsigned* h1q = h1hu + q * 4;
  for (int j = 0; j < dmax; j += 4) {
    int4 ra = *(const int4*)(bk + j);      // records j, j+1
    int4 rb = *(const int4*)(bk + j + 2);  // records j+2, j+3
    bool a0 = j < dg, a1 = j + 1 < dg, a2 = j + 2 < dg, a3 = j + 3 < dg;
    int4 z = make_int4(0, 0, 0, 0);
    int4 hv0 = a0 ? *(const int4*)(h1q + (size_t)(ra.x & 0xFFFF) * 16) : z;
    int4 hv1 = a1 ? *(const int4*)(h1q + (size_t)(ra.z & 0xFFFF) * 16) : z;
    int4 hv2 = a2 ? *(const int4*)(h1q + (size_t)(rb.x & 0xFFFF) * 16) : z;
    int4 hv3 = a3 ? *(const int4*)(h1q + (size_t)(rb.z & 0xFFFF) * 16) : z;
    float bf; int Kc;
    if (a0) { dec2(ra.x, ra.y, c, bf, Kc); rmw16(Tr, Kc, q, bf, hv0); }
    if (a1) { dec2(ra.z, ra.w, c, bf, Kc); rmw16(Tr, Kc, q, bf, hv1); }
    if (a2) { dec2(rb.x, rb.y, c, bf, Kc); rmw16(Tr, Kc, q, bf, hv2); }
    if (a3) { dec2(rb.z, rb.w, c, bf, Kc); rmw16(Tr, Kc, q, bf, hv3); }
  }
  __syncthreads();
  // MFMA: wave wv -> feats [wv*16, wv*16+16), K=832 (26 iters).
  int m = l & 15, quad = l >> 4;
  const char* abase = (const char*)T + m * 1680 + quad * 16;
  const __half* bbase = W2T + (size_t)(wv * 16 + m) * 832 + quad * 8;
  float4v acc = {0.f, 0.f, 0.f, 0.f};
  for (int it = 0; it < 26; it++) {
    half8 af = *(const half8*)(abase + it * 64);
    half8 bf = *(const half8*)(bbase + it * 32);
    acc = __builtin_amdgcn_mfma_f32_16x16x32_f16(af, bf, acc, 0, 0, 0);
  }
  int feat = wv * 16 + m;
  float bb = b2[feat];
  float psum = 0.f;
#pragma unroll
  for (int r = 0; r < 4; r++) {
    int node = quad * 4 + r;
    psum += eluf(acc[r] * invdeg_s[node] + bb);
  }
  // reduce over quad (nodes) -> full 16-node sum per feat; 800 nodes per
  // group and 800 % L2N == 0, so the whole block is in one group.
  psum += __shfl_xor(psum, 16);
  psum += __shfl_xor(psum, 32);
  if (l < 16) {
    int g = n0 / 800;
    atomicAdd(&gbuf[g * 64 + feat], psum);
  }
}

// FC(64->30) + log_softmax on pooled sums. gbuf holds per-group SUM of elu(h2);
// divide by slice count here. One block (64 thr) per group; lanes 0..29 active.
__global__ __launch_bounds__(64) void fc_ls(const float* __restrict__ gbuf,
                                            const int* __restrict__ slices,
                                            const float* __restrict__ fcw,
                                            const float* __restrict__ fcb,
                                            float* __restrict__ out) {
  int g = blockIdx.x;
  int l = threadIdx.x;
  float scale = 1.f / fmaxf((float)(slices[g + 1] - slices[g]), 1.f);
  float logit = -INFINITY;
  if (l < 30) {
    float acc = fcb[l];
    for (int i = 0; i < 64; i++) acc += gbuf[g * 64 + i] * scale * fcw[i * 30 + l];
    logit = acc;
  }
  float m = logit;
  for (int off = 16; off; off >>= 1) m = fmaxf(m, __shfl_xor(m, off, 32));
  float e = (l < 30) ? expf(logit - m) : 0.f;
  for (int off = 16; off; off >>= 1) e += __shfl_xor(e, off, 32);
  if (l < 30) out[g * 30 + l] = logit - m - logf(e);
}

extern "C" void kernel_launch(void* const* d_in, const int* in_sizes, int n_in,
                              void* d_out, int out_size, void* d_ws, size_t ws_size,
                              hipStream_t stream) {
  const float* x      = (const float*)d_in[0];
  const int*   ei     = (const int*)d_in[1];
  const float* pseudo = (const float*)d_in[2];
  const int*   slices = (const int*)d_in[3];
  const float* W1     = (const float*)d_in[4];
  const float* root1  = (const float*)d_in[5];
  const float* b1     = (const float*)d_in[6];
  const float* W2     = (const float*)d_in[7];
  const float* root2  = (const float*)d_in[8];
  const float* b2     = (const float*)d_in[9];
  const float* fcw    = (const float*)d_in[10];
  const float* fcb    = (const float*)d_in[11];
  float* out = (float*)d_out;

  char* ws = (char*)d_ws;
  int*      cnt    = (int*)ws;                                    // N ints
  int2*     bucket = (int2*)(cnt + N_NODES);                      // N*CAP int2 (26.2 MB)
  unsigned* h1h    = (unsigned*)(bucket + (size_t)N_NODES * CAP); // N*16 dwords (fp16 h1)
  float*    gbuf   = (float*)(h1h + (size_t)N_NODES * 16);        // 64*64 fp32
  unsigned* xh     = (unsigned*)(gbuf + 64 * 64);                 // N*4 dwords (fp16 x)
  __half*   W1T    = (__half*)(xh + (size_t)N_NODES * 4);         // 32*224
  __half*   W2T    = W1T + 32 * 224;                              // 64*832

  hipMemsetAsync(cnt, 0, N_NODES * sizeof(int), stream);

  prep<<<1852, 256, 0, stream>>>(x, W1, root1, W2, root2,
                                 (__half*)xh, W1T, W2T, gbuf);
  scatter_eid<<<N_EDGES / 1024, 256, 0, stream>>>(ei, pseudo, cnt, bucket);
  fused_l1<<<N_NODES / L1N, 256, 0, stream>>>(bucket, cnt, xh, W1T, b1,
                                              (unsigned short*)h1h);
  fused_l2<<<N_NODES / L2N, 256, 0, stream>>>(bucket, cnt, h1h, W2T, b2, gbuf);
  fc_ls<<<NB, 64, 0, stream>>>(gbuf, slices, fcw, fcb, out);
}

// Round 11
// 221.518 us; speedup vs baseline: 4.1507x; 1.0741x over previous
//
#include <hip/hip_runtime.h>
#include <hip/hip_fp16.h>
#include <math.h>

#define N_NODES 51200
#define N_EDGES 819200
#define NB 64
#define CAP 64  // max in-degree; Binomial(E,1/N) mean 16, P(>=64) ~ 1e-19

typedef _Float16 half8 __attribute__((ext_vector_type(8)));
typedef __attribute__((ext_vector_type(4))) float float4v;

__device__ __forceinline__ float eluf(float x) {
  return x > 0.f ? x : expm1f(x);
}

// Decode packed edge record {w0 = src|K<<16, w1 = half2(f0,f1)} for corner c.
__device__ __forceinline__ void dec2(int w0, int w1, int c, float& basf, int& Kc) {
  int K = w0 >> 16;  // src < 65536, K <= 18 -> w0 >= 0
  float f0 = __half2float(__ushort_as_half((unsigned short)(w1 & 0xFFFF)));
  float f1 = __half2float(__ushort_as_half((unsigned short)(((unsigned)w1) >> 16)));
  float b0 = (c & 2) ? f0 : 1.f - f0;
  float bv = (c & 1) ? f1 : 1.f - f1;
  Kc = K + (c >> 1) * 5 + (c & 1);
  basf = b0 * bv;
}

// 16B LDS RMW: T row chunk [Kc*16 + q*4 .. +3] (+4 half2 fma).
__device__ __forceinline__ void rmw16(unsigned* Tr, int Kc, int q, float bf, int4 hv) {
  __half2 bas = __float2half2_rn(bf);
  __half2* tp = (__half2*)&Tr[Kc * 16 + q * 4];
  const __half2* h = (const __half2*)&hv;
  __half2 t0 = tp[0], t1 = tp[1], t2 = tp[2], t3 = tp[3];
  tp[0] = __hfma2(bas, h[0], t0);
  tp[1] = __hfma2(bas, h[1], t1);
  tp[2] = __hfma2(bas, h[2], t2);
  tp[3] = __hfma2(bas, h[3], t3);
}

// Prep: xcast (N x 7 fp32 -> N x 8 fp16) | W1T | W2T | zero gbuf. Grid 1852.
__global__ __launch_bounds__(256) void prep(const float* __restrict__ x,
                                            const float* __restrict__ W1,
                                            const float* __restrict__ root1,
                                            const float* __restrict__ W2,
                                            const float* __restrict__ root2,
                                            __half* __restrict__ xh,
                                            __half* __restrict__ W1T,
                                            __half* __restrict__ W2T,
                                            float* __restrict__ gbuf) {
  int b = blockIdx.x, tid = threadIdx.x;
  if (b < 1600) {                       // xcast: N*8 = 409600
    int idx = b * 256 + tid;
    int n = idx >> 3, j = idx & 7;
    xh[idx] = __float2half((j < 7) ? x[n * 7 + j] : 0.f);
  } else if (b < 1628) {                // W1T: 32 feats x 224 = 7168
    int idx = (b - 1600) * 256 + tid;
    int o = idx / 224, k = idx - o * 224;
    float v = 0.f;
    if (k < 200) {
      int cell = k >> 3, f = k & 7;
      if (f < 7) v = W1[(cell * 7 + f) * 32 + o];
    } else if (k < 207) {
      v = root1[(k - 200) * 32 + o];
    }
    W1T[idx] = __float2half(v);
  } else if (b < 1836) {                // W2T: 64 feats x 832 = 53248
    int idx = (b - 1628) * 256 + tid;
    int o = idx / 832, k = idx - o * 832;
    float v = (k < 800) ? W2[k * 64 + o] : root2[(k - 800) * 64 + o];
    W2T[idx] = __float2half(v);
  } else {                              // zero gbuf: 64*64 = 4096
    int idx = (b - 1836) * 256 + tid;
    gbuf[idx] = 0.f;
  }
}

// Build dst-CSR with fixed-capacity buckets; 4 edges per thread (4 independent
// atomic chains in flight). cnt doubles as degree.
__global__ __launch_bounds__(256) void scatter_eid(const int* __restrict__ ei,
                                                   const float* __restrict__ pseudo,
                                                   int* __restrict__ cnt,
                                                   int2* __restrict__ bucket) {
  int base = blockIdx.x * 1024 + threadIdx.x;
#pragma unroll
  for (int u = 0; u < 4; u++) {
    int e = base + u * 256;
    int src = ei[e], dst = ei[N_EDGES + e];
    float v0 = pseudo[2 * e] * 4.f;
    float v1 = pseudo[2 * e + 1] * 4.f;
    int lo0 = min(max((int)floorf(v0), 0), 3);
    int lo1 = min(max((int)floorf(v1), 0), 3);
    float f0 = v0 - (float)lo0, f1 = v1 - (float)lo1;
    int K = lo0 * 5 + lo1;  // corners at K, K+1, K+5, K+6
    unsigned short u0 = __half_as_ushort(__float2half(f0));
    unsigned short u1 = __half_as_ushort(__float2half(f1));
    int w0 = src | (K << 16);
    int w1 = (int)((unsigned)u0 | ((unsigned)u1 << 16));
    int slot = atomicAdd(&cnt[dst], 1);
    if (slot < CAP) bucket[(size_t)dst * CAP + slot] = make_int2(w0, w1);
  }
}

// Layer 1 fused: T[16 nodes][224 halves] in LDS; Phase A: 4 nodes in parallel
// per wave (lane = slot|corner|pair), software-pipelined edge loop (records
// prefetched 2 iters ahead, x-gathers 1 iter ahead); then MFMA f16:
// h1 = elu( ([T | deg*x] @ [W1;root1]T) * invdeg + b1 ), fp16 out.
#define L1N 16
__global__ __launch_bounds__(256) void fused_l1(const int2* __restrict__ bucket,
                                                const int* __restrict__ cnt,
                                                const unsigned* __restrict__ xh,   // N x 4 dwords
                                                const __half* __restrict__ W1T,
                                                const float* __restrict__ b1,
                                                unsigned short* __restrict__ h1h) {
  __shared__ unsigned T[L1N * 112];  // 7.2 KB
  __shared__ float invdeg_s[L1N];
  int tid = threadIdx.x;
  int n0 = blockIdx.x * L1N;
  for (int idx = tid; idx < L1N * 112; idx += 256) T[idx] = 0u;
  if (tid < L1N) invdeg_s[tid] = 1.f / fmaxf((float)cnt[n0 + tid], 1.f);
  __syncthreads();
  // append max(deg,1)*x at dwords 100..103 (Phase A touches dwords < 100).
  if (tid < L1N * 4) {
    int row = tid >> 2, p = tid & 3;
    int n = n0 + row;
    float dgc = fmaxf((float)cnt[n], 1.f);
    unsigned xv = xh[n * 4 + p];
    __half2 h = __hmul2(*(const __half2*)&xv, __float2half2_rn(dgc));
    T[row * 112 + 100 + p] = *(unsigned*)&h;
  }
  int wv = tid >> 6, l = tid & 63;
  int slot = l >> 4, c = (l >> 2) & 3, p = l & 3;
  int nn = wv * 4 + slot;
  int n = n0 + nn;
  int dg = min(cnt[n], CAP);
  int dmax = dg;
  dmax = max(dmax, __shfl_xor(dmax, 16));
  dmax = max(dmax, __shfl_xor(dmax, 32));
  const int2* bk = bucket + (size_t)n * CAP;
  unsigned* Tr = &T[nn * 112];
  // pipeline prologue: records for iters 0,1; x-gathers for iter 0.
  int4 ra0 = *(const int4*)(bk + 0);
  int4 rb0 = *(const int4*)(bk + 2);
  int4 ra1 = *(const int4*)(bk + 4);
  int4 rb1 = *(const int4*)(bk + 6);
  unsigned xv0 = xh[(ra0.x & 0xFFFF) * 4 + p];
  unsigned xv1 = xh[(ra0.z & 0xFFFF) * 4 + p];
  unsigned xv2 = xh[(rb0.x & 0xFFFF) * 4 + p];
  unsigned xv3 = xh[(rb0.z & 0xFFFF) * 4 + p];
  for (int j = 0; j < dmax; j += 4) {
    int jp = min(j + 8, CAP - 4);               // records 2 iters ahead
    int4 ra2 = *(const int4*)(bk + jp);
    int4 rb2 = *(const int4*)(bk + jp + 2);
    unsigned nx0 = xh[(ra1.x & 0xFFFF) * 4 + p];  // gathers 1 iter ahead
    unsigned nx1 = xh[(ra1.z & 0xFFFF) * 4 + p];
    unsigned nx2 = xh[(rb1.x & 0xFFFF) * 4 + p];
    unsigned nx3 = xh[(rb1.z & 0xFFFF) * 4 + p];
    bool a0 = j < dg, a1 = j + 1 < dg, a2 = j + 2 < dg, a3 = j + 3 < dg;
    float bf; int Kc;
    if (a0) { dec2(ra0.x, ra0.y, c, bf, Kc);
      __half2* tp = (__half2*)&Tr[Kc * 4 + p];
      *tp = __hfma2(__float2half2_rn(bf), *(const __half2*)&xv0, *tp); }
    if (a1) { dec2(ra0.z, ra0.w, c, bf, Kc);
      __half2* tp = (__half2*)&Tr[Kc * 4 + p];
      *tp = __hfma2(__float2half2_rn(bf), *(const __half2*)&xv1, *tp); }
    if (a2) { dec2(rb0.x, rb0.y, c, bf, Kc);
      __half2* tp = (__half2*)&Tr[Kc * 4 + p];
      *tp = __hfma2(__float2half2_rn(bf), *(const __half2*)&xv2, *tp); }
    if (a3) { dec2(rb0.z, rb0.w, c, bf, Kc);
      __half2* tp = (__half2*)&Tr[Kc * 4 + p];
      *tp = __hfma2(__float2half2_rn(bf), *(const __half2*)&xv3, *tp); }
    ra0 = ra1; rb0 = rb1; ra1 = ra2; rb1 = rb2;
    xv0 = nx0; xv1 = nx1; xv2 = nx2; xv3 = nx3;
  }
  __syncthreads();
  // MFMA: waves 0,1 -> feat tiles 0,1; M=16 nodes, K=224 (7 iters).
  if (wv < 2) {
    int m = l & 15, quad = l >> 4;
    const char* abase = (const char*)T + m * 448 + quad * 16;
    const __half* bbase = W1T + (wv * 16 + m) * 224 + quad * 8;
    float4v acc = {0.f, 0.f, 0.f, 0.f};
#pragma unroll
    for (int it = 0; it < 7; it++) {
      half8 af = *(const half8*)(abase + it * 64);
      half8 bf = *(const half8*)(bbase + it * 32);
      acc = __builtin_amdgcn_mfma_f32_16x16x32_f16(af, bf, acc, 0, 0, 0);
    }
    int feat = wv * 16 + m;
    float bb = b1[feat];
#pragma unroll
    for (int r = 0; r < 4; r++) {
      int row = quad * 4 + r;
      float v = eluf(acc[r] * invdeg_s[row] + bb);
      h1h[(size_t)(n0 + row) * 32 + feat] = __half_as_ushort(__float2half(v));
    }
  }
}

// Layer 2 fused: T[16 nodes][840 halves] in LDS; Phase A: 4 nodes in parallel
// per wave (lane = slot|corner|quarter, 16B b128 RMW), software-pipelined
// edge loop; MFMA f16 epilogue computes elu rows AND pool-reduces them into
// gbuf via one atomicAdd per (block, feat). h2 is never materialized.
#define L2N 16
__global__ __launch_bounds__(256) void fused_l2(const int2* __restrict__ bucket,
                                                const int* __restrict__ cnt,
                                                const unsigned* __restrict__ h1hu,  // N x 16 dwords
                                                const __half* __restrict__ W2T,
                                                const float* __restrict__ b2,
                                                float* __restrict__ gbuf) {
  __shared__ unsigned T[L2N * 420];  // 26.9 KB
  __shared__ float invdeg_s[L2N];
  int tid = threadIdx.x;
  int n0 = blockIdx.x * L2N;
  for (int idx = tid; idx < L2N * 420; idx += 256) T[idx] = 0u;
  if (tid < L2N) invdeg_s[tid] = 1.f / fmaxf((float)cnt[n0 + tid], 1.f);
  __syncthreads();
  // append max(deg,1)*h1 at dwords 400..415 (Phase A touches dwords < 400).
  {
    int row = tid >> 4, p = tid & 15;
    int n = n0 + row;
    float dgc = fmaxf((float)cnt[n], 1.f);
    unsigned hv = h1hu[(size_t)n * 16 + p];
    __half2 h = __hmul2(*(const __half2*)&hv, __float2half2_rn(dgc));
    T[row * 420 + 400 + p] = *(unsigned*)&h;
  }
  int wv = tid >> 6, l = tid & 63;
  int slot = l >> 4, c = (l >> 2) & 3, q = l & 3;
  int nn = wv * 4 + slot;
  int n = n0 + nn;
  int dg = min(cnt[n], CAP);
  int dmax = dg;
  dmax = max(dmax, __shfl_xor(dmax, 16));
  dmax = max(dmax, __shfl_xor(dmax, 32));
  const int2* bk = bucket + (size_t)n * CAP;
  unsigned* Tr = &T[nn * 420];
  const unsigned* h1q = h1hu + q * 4;
  // pipeline prologue: records for iters 0,1; h1-gathers for iter 0.
  int4 ra0 = *(const int4*)(bk + 0);
  int4 rb0 = *(const int4*)(bk + 2);
  int4 ra1 = *(const int4*)(bk + 4);
  int4 rb1 = *(const int4*)(bk + 6);
  int4 hv0 = *(const int4*)(h1q + (size_t)(ra0.x & 0xFFFF) * 16);
  int4 hv1 = *(const int4*)(h1q + (size_t)(ra0.z & 0xFFFF) * 16);
  int4 hv2 = *(const int4*)(h1q + (size_t)(rb0.x & 0xFFFF) * 16);
  int4 hv3 = *(const int4*)(h1q + (size_t)(rb0.z & 0xFFFF) * 16);
  for (int j = 0; j < dmax; j += 4) {
    int jp = min(j + 8, CAP - 4);               // records 2 iters ahead
    int4 ra2 = *(const int4*)(bk + jp);
    int4 rb2 = *(const int4*)(bk + jp + 2);
    int4 nh0 = *(const int4*)(h1q + (size_t)(ra1.x & 0xFFFF) * 16);  // 1 ahead
    int4 nh1 = *(const int4*)(h1q + (size_t)(ra1.z & 0xFFFF) * 16);
    int4 nh2 = *(const int4*)(h1q + (size_t)(rb1.x & 0xFFFF) * 16);
    int4 nh3 = *(const int4*)(h1q + (size_t)(rb1.z & 0xFFFF) * 16);
    bool a0 = j < dg, a1 = j + 1 < dg, a2 = j + 2 < dg, a3 = j + 3 < dg;
    float bf; int Kc;
    if (a0) { dec2(ra0.x, ra0.y, c, bf, Kc); rmw16(Tr, Kc, q, bf, hv0); }
    if (a1) { dec2(ra0.z, ra0.w, c, bf, Kc); rmw16(Tr, Kc, q, bf, hv1); }
    if (a2) { dec2(rb0.x, rb0.y, c, bf, Kc); rmw16(Tr, Kc, q, bf, hv2); }
    if (a3) { dec2(rb0.z, rb0.w, c, bf, Kc); rmw16(Tr, Kc, q, bf, hv3); }
    ra0 = ra1; rb0 = rb1; ra1 = ra2; rb1 = rb2;
    hv0 = nh0; hv1 = nh1; hv2 = nh2; hv3 = nh3;
  }
  __syncthreads();
  // MFMA: wave wv -> feats [wv*16, wv*16+16), K=832 (26 iters).
  int m = l & 15, quad = l >> 4;
  const char* abase = (const char*)T + m * 1680 + quad * 16;
  const __half* bbase = W2T + (size_t)(wv * 16 + m) * 832 + quad * 8;
  float4v acc = {0.f, 0.f, 0.f, 0.f};
  for (int it = 0; it < 26; it++) {
    half8 af = *(const half8*)(abase + it * 64);
    half8 bf = *(const half8*)(bbase + it * 32);
    acc = __builtin_amdgcn_mfma_f32_16x16x32_f16(af, bf, acc, 0, 0, 0);
  }
  int feat = wv * 16 + m;
  float bb = b2[feat];
  float psum = 0.f;
#pragma unroll
  for (int r = 0; r < 4; r++) {
    int node = quad * 4 + r;
    psum += eluf(acc[r] * invdeg_s[node] + bb);
  }
  // reduce over quad (nodes) -> full 16-node sum per feat; 800 nodes per
  // group and 800 % L2N == 0, so the whole block is in one group.
  psum += __shfl_xor(psum, 16);
  psum += __shfl_xor(psum, 32);
  if (l < 16) {
    int g = n0 / 800;
    atomicAdd(&gbuf[g * 64 + feat], psum);
  }
}

// FC(64->30) + log_softmax on pooled sums. gbuf holds per-group SUM of elu(h2);
// divide by slice count here. One block (64 thr) per group; lanes 0..29 active.
__global__ __launch_bounds__(64) void fc_ls(const float* __restrict__ gbuf,
                                            const int* __restrict__ slices,
                                            const float* __restrict__ fcw,
                                            const float* __restrict__ fcb,
                                            float* __restrict__ out) {
  int g = blockIdx.x;
  int l = threadIdx.x;
  float scale = 1.f / fmaxf((float)(slices[g + 1] - slices[g]), 1.f);
  float logit = -INFINITY;
  if (l < 30) {
    float acc = fcb[l];
    for (int i = 0; i < 64; i++) acc += gbuf[g * 64 + i] * scale * fcw[i * 30 + l];
    logit = acc;
  }
  float m = logit;
  for (int off = 16; off; off >>= 1) m = fmaxf(m, __shfl_xor(m, off, 32));
  float e = (l < 30) ? expf(logit - m) : 0.f;
  for (int off = 16; off; off >>= 1) e += __shfl_xor(e, off, 32);
  if (l < 30) out[g * 30 + l] = logit - m - logf(e);
}

extern "C" void kernel_launch(void* const* d_in, const int* in_sizes, int n_in,
                              void* d_out, int out_size, void* d_ws, size_t ws_size,
                              hipStream_t stream) {
  const float* x      = (const float*)d_in[0];
  const int*   ei     = (const int*)d_in[1];
  const float* pseudo = (const float*)d_in[2];
  const int*   slices = (const int*)d_in[3];
  const float* W1     = (const float*)d_in[4];
  const float* root1  = (const float*)d_in[5];
  const float* b1     = (const float*)d_in[6];
  const float* W2     = (const float*)d_in[7];
  const float* root2  = (const float*)d_in[8];
  const float* b2     = (const float*)d_in[9];
  const float* fcw    = (const float*)d_in[10];
  const float* fcb    = (const float*)d_in[11];
  float* out = (float*)d_out;

  char* ws = (char*)d_ws;
  int*      cnt    = (int*)ws;                                    // N ints
  int2*     bucket = (int2*)(cnt + N_NODES);                      // N*CAP int2 (26.2 MB)
  unsigned* h1h    = (unsigned*)(bucket + (size_t)N_NODES * CAP); // N*16 dwords (fp16 h1)
  float*    gbuf   = (float*)(h1h + (size_t)N_NODES * 16);        // 64*64 fp32
  unsigned* xh     = (unsigned*)(gbuf + 64 * 64);                 // N*4 dwords (fp16 x)
  __half*   W1T    = (__half*)(xh + (size_t)N_NODES * 4);         // 32*224
  __half*   W2T    = W1T + 32 * 224;                              // 64*832

  hipMemsetAsync(cnt, 0, N_NODES * sizeof(int), stream);

  prep<<<1852, 256, 0, stream>>>(x, W1, root1, W2, root2,
                                 (__half*)xh, W1T, W2T, gbuf);
  scatter_eid<<<N_EDGES / 1024, 256, 0, stream>>>(ei, pseudo, cnt, bucket);
  fused_l1<<<N_NODES / L1N, 256, 0, stream>>>(bucket, cnt, xh, W1T, b1,
                                              (unsigned short*)h1h);
  fused_l2<<<N_NODES / L2N, 256, 0, stream>>>(bucket, cnt, h1h, W2T, b2, gbuf);
  fc_ls<<<NB, 64, 0, stream>>>(gbuf, slices, fcw, fcb, out);
}